// Round 8
// baseline (331.056 us; speedup 1.0000x reference)
//
#include <hip/hip_runtime.h>

typedef __attribute__((ext_vector_type(8))) short bf16x8;
typedef __attribute__((ext_vector_type(4))) float f32x4;
typedef __attribute__((ext_vector_type(4))) unsigned short u16x4;
typedef __attribute__((ext_vector_type(2))) unsigned short u16x2;
typedef __attribute__((ext_vector_type(8))) unsigned short u16x8;

#define GLD16(g, l) __builtin_amdgcn_global_load_lds( \
    (const __attribute__((address_space(1))) void*)(g), \
    (__attribute__((address_space(3))) void*)(l), 16, 0, 0)

__device__ __forceinline__ unsigned short f2bf(float f) {
  unsigned u = __float_as_uint(f);
  unsigned r = u + 0x7FFFu + ((u >> 16) & 1u);
  return (unsigned short)(r >> 16);
}
__device__ __forceinline__ float bf2f(unsigned short h) {
  return __uint_as_float(((unsigned)h) << 16);
}

template <int N>
__device__ __forceinline__ void wait_vm() {
  if constexpr (N == 0) asm volatile("s_waitcnt vmcnt(0)" ::: "memory");
  else if constexpr (N == 6) asm volatile("s_waitcnt vmcnt(6)" ::: "memory");
  else static_assert(N == 0, "unsupported vmcnt");
}

// ---------------- prep kernels ----------------

__global__ void k_weff(const float* __restrict__ alpha,
                       const float* __restrict__ dw1,
                       const float* __restrict__ dw3,
                       const float* __restrict__ dw5,
                       float* __restrict__ weff) {
  int tap = blockIdx.x;        // 0..24
  int c = threadIdx.x;         // 0..255
  int dy = tap / 5, dx = tap % 5;
  float v = alpha[3] * dw5[c * 25 + tap];
  if (dy >= 1 && dy <= 3 && dx >= 1 && dx <= 3)
    v += alpha[2] * dw3[c * 9 + (dy - 1) * 3 + (dx - 1)];
  if (tap == 12) v += alpha[1] * dw1[c] + alpha[0];
  weff[tap * 256 + c] = v;
}

// combined weights with INTERLEAVED kv row order (R14-verified harmless, kept).
// Row map: k1[c]->2c, v1[c]->2c+1, k3[c]->512+2c, v3[c]->512+2c+1, Wr[c]->1024+c.
__global__ void k_combine(const float* __restrict__ Wk,
                          const float* __restrict__ Wv,
                          const float* __restrict__ Wr,
                          const float* __restrict__ Wf,
                          const float* __restrict__ Wb,
                          const float* __restrict__ bfv,
                          const float* __restrict__ bbv,
                          short* __restrict__ wcat,
                          float* __restrict__ bias) {
  int mat = blockIdx.x >> 8;   // 0:k1 1:k3 2:v1 3:v3 4:r
  int i = blockIdx.x & 255;
  int j = threadIdx.x;
  if (mat == 4) {
    wcat[(size_t)(1024 + i) * 256 + j] = (short)f2bf(Wr[i * 256 + j]);
    if (j == 0) bias[1024 + i] = 0.f;
    return;
  }
  const float* Am = (mat & 1) ? Wb : Wf;
  const float* Bm = (mat < 2) ? Wk : Wv;
  const float* arow = Am + i * 256;
  float acc = 0.f;
  for (int m = 0; m < 256; ++m) acc += arow[m] * Bm[m * 256 + j];
  int newrow = ((mat & 1) << 9) + (i << 1) + (mat >> 1);  // interleaved position
  wcat[(size_t)newrow * 256 + j] = (short)f2bf(acc);
  if (j == 0) bias[newrow] = (mat & 1) ? bbv[i] : bfv[i];
}

__global__ void k_wo(const float* __restrict__ Wo, short* __restrict__ wob) {
  int i = blockIdx.x * 256 + threadIdx.x;
  wob[i] = (short)f2bf(Wo[i]);
}

// ---------------- OmniShift: 2-row register sliding-window 5x5 stencil ----------
// R13-verified: w-tile 8, grid (8,32,B) = 2048 blocks = 8 blocks/CU, 32 waves/CU.
__global__ __launch_bounds__(256, 8)
void k_shift(const float* __restrict__ x, const float* __restrict__ weff,
             unsigned short* __restrict__ xf) {
  int c = threadIdx.x;
  int w0 = blockIdx.x * 8;    // 0,8,...,56
  int h0 = blockIdx.y * 2;    // 0..62
  int b = blockIdx.z;

  float wg[5][5];
#pragma unroll
  for (int dy = 0; dy < 5; ++dy)
#pragma unroll
    for (int dx = 0; dx < 5; ++dx)
      wg[dy][dx] = weff[(dy * 5 + dx) * 256 + c];

  const float* xb = x + (size_t)b * 4096 * 256 + c;
  int rowoff[6];
  bool rv[6];
#pragma unroll
  for (int r = 0; r < 6; ++r) {
    int y = h0 + r - 2;
    rv[r] = (y >= 0 && y < 64);
    int yc = y < 0 ? 0 : (y > 63 ? 63 : y);
    rowoff[r] = yc * 64 * 256;
  }

  float win[6][8];
#pragma unroll
  for (int j = -2; j <= 1; ++j) {
    int xx = w0 + j;
    int slot = j & 7;                 // w0 % 8 == 0 -> static
    bool xv = (xx >= 0);
    int xc = xx < 0 ? 0 : xx;
#pragma unroll
    for (int r = 0; r < 6; ++r) {
      float v = xb[rowoff[r] + xc * 256];
      win[r][slot] = (xv && rv[r]) ? v : 0.f;
    }
  }

  unsigned short* xo = xf + ((size_t)b * 4096 + (size_t)h0 * 64) * 256 + c;
#pragma unroll
  for (int ui = 0; ui < 8; ++ui) {
    int w = w0 + ui;
    {
      int xx = w + 2;
      int slot = (ui + 2) & 7;        // static
      bool xv = (xx < 64);
      int xc = xx > 63 ? 63 : xx;
#pragma unroll
      for (int r = 0; r < 6; ++r) {
        float v = xb[rowoff[r] + xc * 256];
        win[r][slot] = (xv && rv[r]) ? v : 0.f;
      }
    }
#pragma unroll
    for (int j = 0; j < 2; ++j) {
      float a0 = 0.f, a1 = 0.f, a2 = 0.f, a3 = 0.f, a4 = 0.f;
#pragma unroll
      for (int dx = 0; dx < 5; ++dx) {
        int slot = (ui - 2 + dx) & 7; // static
        a0 = fmaf(win[j + 0][slot], wg[0][dx], a0);
        a1 = fmaf(win[j + 1][slot], wg[1][dx], a1);
        a2 = fmaf(win[j + 2][slot], wg[2][dx], a2);
        a3 = fmaf(win[j + 3][slot], wg[3][dx], a3);
        a4 = fmaf(win[j + 4][slot], wg[4][dx], a4);
      }
      xo[((size_t)j * 64 + w) * 256] = f2bf(((a0 + a1) + (a2 + a3)) + a4);
    }
  }
}

// ---------------- gemm1: 256x128 tile, 8 waves, single-buffer (R23) -------------
// out = xf[32768][256] @ wcat[1280][256]^T -> kv (bf16) / srb (sigmoid bf16).
// R7 lesson: gemm1 stuck ~52 us across 3 structures at 16 waves/CU, Occ 28%,
// all pipes <28% busy -> bound by per-block serial overhead x low residency.
// R23: 8-wave 512-thread block, 256x128 tile, LDS = A 32K + B 16K = 48 KB ->
// 3 blocks/CU = 24 waves/CU (+50% TLP); 1280 blocks (half the pro/epilogue
// instances); 256 MFMA per K-step per block at the same 2-barrier cost.
// Per-thread shape IDENTICAL to the proven BM=128 kernel (MI=4, acc 64 VGPR,
// measured 60) -> at 6 waves/SIMD cap=85, no spill (R5 lesson).
// BK=64: 8-chunk XOR swizzle covers all 32 banks -> 0 conflicts (R7 lesson:
// BK=32's 4-chunk swizzle collides 4-way). NT=10 XCD A-locality kept (R3:
// FETCH 27->14.5 MB); per-XCD A footprint 2 MB < 4 MB L2.
__global__ __launch_bounds__(512, 6)
void k_gemm1b(const short* __restrict__ A, const short* __restrict__ Bm,
              const float* __restrict__ bias,
              unsigned short* __restrict__ kv, unsigned short* __restrict__ srb,
              int M) {
  constexpr int BM = 256, BK = 64;
  constexpr int AE = BM * BK;              // 16384 shorts
  constexpr int RW = 132;                  // padded epilogue row width (f32)
  __shared__ __align__(16) short lds[AE + 128 * BK];   // 48 KB

  int t = threadIdx.x;
  int lane = t & 63, wv = t >> 6;          // 8 waves
  int wr = wv >> 1, wc = wv & 1;           // wr 0..3 (m), wc 0..1 (n)
  int x = blockIdx.x & 7;
  int j = blockIdx.x >> 3;
  int mpx = M / (BM * 8);                  // m-tiles per XCD (16)
  int m0 = (x * mpx + j / 10) * BM;
  int n0 = (j % 10) * 128;
  f32x4 acc[4][4] = {};

  float bb[4];
#pragma unroll
  for (int ni = 0; ni < 4; ++ni)
    bb[ni] = bias[n0 + wc * 64 + ni * 16 + (lane & 15)];

  for (int k0 = 0; k0 < 256; k0 += BK) {
    // STAGE: linear LDS dest, XOR-swizzled global source chunk
#pragma unroll
    for (int i = 0; i < 4; ++i) {
      int cc = t + i * 512;
      int row = cc >> 3, kc = cc & 7;
      GLD16(A + (size_t)(m0 + row) * 256 + k0 + ((kc ^ (row & 7)) << 3), &lds[cc * 8]);
    }
#pragma unroll
    for (int i = 0; i < 2; ++i) {
      int cc = t + i * 512;
      int row = cc >> 3, kc = cc & 7;
      GLD16(Bm + (size_t)(n0 + row) * 256 + k0 + ((kc ^ (row & 7)) << 3), &lds[AE + cc * 8]);
    }
    __syncthreads();
#pragma unroll
    for (int kk = 0; kk < 2; ++kk) {
      int ch = kk * 4 + (lane >> 4);
      bf16x8 av[4], bv[4];
#pragma unroll
      for (int i = 0; i < 4; ++i) {
        int row = wr * 64 + i * 16 + (lane & 15);
        av[i] = *(const bf16x8*)&lds[row * BK + ((ch ^ (row & 7)) << 3)];
      }
#pragma unroll
      for (int i = 0; i < 4; ++i) {
        int row = wc * 64 + i * 16 + (lane & 15);
        bv[i] = *(const bf16x8*)&lds[AE + row * BK + ((ch ^ (row & 7)) << 3)];
      }
#pragma unroll
      for (int mi = 0; mi < 4; ++mi)
#pragma unroll
        for (int ni = 0; ni < 4; ++ni)
          acc[mi][ni] = __builtin_amdgcn_mfma_f32_16x16x32_bf16(av[mi], bv[ni], acc[mi][ni], 0, 0, 0);
    }
    __syncthreads();
  }

  // ---- epilogue: LDS transpose (row-major fl [64][132]) -> wide stores ----
  // 33.8 KB < 48 KB LDS. Same verified 0-conflict pattern as the 128-tile
  // kernel, generalized: fl row = wr*16 + (lane>>4)*4 + j, 64 rows.
  float* fl = (float*)lds;
  int rrow = t >> 3;               // 0..63
  int colb = (t & 7) * 16;
#pragma unroll
  for (int mi = 0; mi < 4; ++mi) {
    if (mi) __syncthreads();       // previous readout done before overwrite
    {
      int r0 = (lane >> 4) * 4;
#pragma unroll
      for (int ni = 0; ni < 4; ++ni) {
        int colL = wc * 64 + (lane & 15) + ni * 16;
        f32x4 v = acc[mi][ni];
#pragma unroll
        for (int jj = 0; jj < 4; ++jj)
          fl[(wr * 16 + r0 + jj) * RW + colL] = v[jj] + bb[ni];
      }
    }
    __syncthreads();
    float vv[16];
#pragma unroll
    for (int q = 0; q < 4; ++q)
      *(f32x4*)&vv[q * 4] = *(const f32x4*)&fl[rrow * RW + colb + q * 4];
    int grow = m0 + (rrow >> 4) * 64 + mi * 16 + (rrow & 15);
    u16x8 o0, o1;
    if (n0 < 1024) {
#pragma unroll
      for (int q = 0; q < 8; ++q) { o0[q] = f2bf(vv[q]); o1[q] = f2bf(vv[8 + q]); }
      unsigned short* dst = kv + (size_t)grow * 1024 + n0 + colb;
      *(u16x8*)dst = o0;
      *(u16x8*)(dst + 8) = o1;
    } else {
#pragma unroll
      for (int q = 0; q < 8; ++q) {
        o0[q] = f2bf(1.f / (1.f + __expf(-vv[q])));
        o1[q] = f2bf(1.f / (1.f + __expf(-vv[8 + q])));
      }
      unsigned short* dst = srb + (size_t)grow * 256 + (n0 - 1024) + colb;
      *(u16x8*)dst = o0;
      *(u16x8*)(dst + 8) = o1;
    }
  }
}

// ---------------- gemm2: double-buffered deep pipeline (R4 exact) ---------------
// R4-verified ~19 us: BM=64/BK=64, NK=16, depth-2 counted-vmcnt pipeline,
// 3 blocks/CU, natural dim3(M/64, 2) grid (R5: XCD remap hurt here -> none).
// Per iter: wait vmcnt(LD) (current step's loads; next step's stay in flight
// ACROSS the barrier), s_barrier, compute, lgkmcnt(0)+s_barrier, stage k+2.
// NEVER __syncthreads in the K-loop (drains vmcnt(0), kills the pipe).
template <int EPI, int BM, int BK>
__global__ __launch_bounds__(256, 3)
void gemm_db(const short* __restrict__ A, const short* __restrict__ Bm,
             const float* __restrict__ bias,
             void* __restrict__ O0, void* __restrict__ O1,
             int M, int N, int K) {
  constexpr int AE = BM * BK;           // shorts in A region of one buffer
  constexpr int BUFS = (BM + 128) * BK; // shorts per buffer
  constexpr int MI = BM / 32;           // m-fragments per wave
  constexpr int CH = BK / 8;            // 16B chunks per row
  constexpr int LA = BM * BK / 2048;    // A gld_lds per thread per step
  constexpr int LB = BK / 16;           // B gld_lds per thread per step
  constexpr int LD = LA + LB;           // loads in flight per step
  constexpr int RW = 132;               // padded row width for epilogue (f32)
  __shared__ __align__(16) short lds[2 * BUFS];

  int t = threadIdx.x;
  int lane = t & 63, wv = t >> 6;
  int wr = wv >> 1, wc = wv & 1;
  int m0 = blockIdx.x * BM, n0 = blockIdx.y * 128;
  const int NK = K / BK;
  f32x4 acc[MI][4] = {};

  float bb[4];
  if (EPI == 0) {
#pragma unroll
    for (int ni = 0; ni < 4; ++ni)
      bb[ni] = bias[n0 + wc * 64 + ni * 16 + (lane & 15)];
  }

  auto STAGE = [&](int step, int bo) {
    int k0 = step * BK;
#pragma unroll
    for (int i = 0; i < LA; ++i) {
      int cc = t + i * 256;
      int row = cc / CH, kc = cc % CH;
      GLD16(A + (size_t)(m0 + row) * K + k0 + ((kc ^ (row & (CH - 1))) << 3),
            &lds[bo + cc * 8]);
    }
#pragma unroll
    for (int i = 0; i < LB; ++i) {
      int cc = t + i * 256;
      int row = cc / CH, kc = cc % CH;
      GLD16(Bm + (size_t)(n0 + row) * K + k0 + ((kc ^ (row & (CH - 1))) << 3),
            &lds[bo + AE + cc * 8]);
    }
  };
  auto COMPUTE = [&](int bo) {
#pragma unroll
    for (int kk = 0; kk < BK / 32; ++kk) {
      int ch = kk * 4 + (lane >> 4);
      bf16x8 av[MI], bv[4];
#pragma unroll
      for (int i = 0; i < MI; ++i) {
        int row = wr * (BM / 2) + i * 16 + (lane & 15);
        av[i] = *(const bf16x8*)&lds[bo + row * BK + ((ch ^ (row & (CH - 1))) << 3)];
      }
#pragma unroll
      for (int i = 0; i < 4; ++i) {
        int row = wc * 64 + i * 16 + (lane & 15);
        bv[i] = *(const bf16x8*)&lds[bo + AE + row * BK + ((ch ^ (row & (CH - 1))) << 3)];
      }
#pragma unroll
      for (int mi = 0; mi < MI; ++mi)
#pragma unroll
        for (int ni = 0; ni < 4; ++ni)
          acc[mi][ni] = __builtin_amdgcn_mfma_f32_16x16x32_bf16(av[mi], bv[ni], acc[mi][ni], 0, 0, 0);
    }
  };

  STAGE(0, 0);
  STAGE(1, BUFS);
#pragma unroll
  for (int k = 0; k < 16; ++k) {      // bounded by max NK; break inside
    if (k >= NK) break;
    int bo = (k & 1) ? BUFS : 0;
    if (k < NK - 1) wait_vm<LD>();
    else wait_vm<0>();
    __builtin_amdgcn_s_barrier();
    COMPUTE(bo);
    asm volatile("s_waitcnt lgkmcnt(0)" ::: "memory");
    __builtin_amdgcn_s_barrier();
    if (k + 2 < NK) STAGE(k + 2, bo);
  }

  // ---- epilogue: LDS transpose (row-major fl) -> coalesced wide stores ----
  float* fl = (float*)lds;   // [32 rows][RW cols] f32 = 16.9 KB
  int rrow = t >> 3;               // 0..31
  int colb = (t & 7) * 16;
#pragma unroll
  for (int mi = 0; mi < MI; ++mi) {
    if (mi) __syncthreads();       // previous readout done before overwrite
    {
      int r0 = (lane >> 4) * 4;
#pragma unroll
      for (int ni = 0; ni < 4; ++ni) {
        int colL = wc * 64 + (lane & 15) + ni * 16;
        f32x4 v = acc[mi][ni];
#pragma unroll
        for (int j = 0; j < 4; ++j) {
          float vj = v[j];
          if (EPI == 0) vj += bb[ni];
          fl[(wr * 16 + r0 + j) * RW + colL] = vj;
        }
      }
    }
    __syncthreads();
    float vv[16];
#pragma unroll
    for (int q = 0; q < 4; ++q)
      *(f32x4*)&vv[q * 4] = *(const f32x4*)&fl[rrow * RW + colb + q * 4];
    int grow = m0 + (rrow >> 4) * (BM / 2) + mi * 16 + (rrow & 15);
    if (EPI == 0) {
      u16x8 o0, o1;
      if (n0 < 1024) {
#pragma unroll
        for (int q = 0; q < 8; ++q) { o0[q] = f2bf(vv[q]); o1[q] = f2bf(vv[8 + q]); }
        unsigned short* dst = (unsigned short*)O0 + (size_t)grow * 1024 + n0 + colb;
        *(u16x8*)dst = o0;
        *(u16x8*)(dst + 8) = o1;
      } else {
#pragma unroll
        for (int q = 0; q < 8; ++q) {
          o0[q] = f2bf(1.f / (1.f + __expf(-vv[q])));
          o1[q] = f2bf(1.f / (1.f + __expf(-vv[8 + q])));
        }
        unsigned short* dst = (unsigned short*)O1 + (size_t)grow * 256 + (n0 - 1024) + colb;
        *(u16x8*)dst = o0;
        *(u16x8*)(dst + 8) = o1;
      }
    } else {
      float* dst = (float*)O0 + (size_t)grow * N + n0 + colb;
#pragma unroll
      for (int q = 0; q < 4; ++q) {
        f32x4 ov = {vv[q * 4], vv[q * 4 + 1], vv[q * 4 + 2], vv[q * 4 + 3]};
        *(f32x4*)(dst + q * 4) = ov;
      }
    }
  }
}

// ---------------- WKV (software-pipelined; 2 ch/thread, interleaved kv) ---------
// R15-verified: explicit x2-unroll prefetch pipeline (4-6 outstanding loads/wave).
// grid 128 x 2(tr) x 8 = 2048 blocks; chunk 32, warmup 16.
__global__ __launch_bounds__(256, 8)
void k_wkv(const unsigned short* __restrict__ kvb, const unsigned short* __restrict__ srb,
           const float* __restrict__ decay, const float* __restrict__ first,
           unsigned short* __restrict__ xssr) {
  const int T = 4096;
  int tid = threadIdx.x;
  int g = tid >> 7;              // 0: k1/v1 half, 1: k3/v3 half
  int l = tid & 127;
  int c0 = l * 2;
  int tr = blockIdx.y;           // 0 natural, 1 transposed scan order
  int s = (g << 1) | tr;         // stream in concat order k1,k2,k3,k4
  int scol = s * 256;
  int chunk = blockIdx.x;        // 0..127, 32 tokens each
  int b = blockIdx.z;
  const float invT = 1.0f / 4096.0f;

  float P0 = 0.f, P1 = 0.f, Q0 = 0.f, Q1 = 0.f;
  float D0 = __expf(-__expf(decay[scol + c0] * invT));
  float D1 = __expf(-__expf(decay[scol + c0 + 1] * invT));
  float eu0 = __expf(first[scol + c0] * invT);
  float eu1 = __expf(first[scol + c0 + 1] * invT);

  int t0 = chunk * 32;
  int tstart = t0 >= 16 ? t0 - 16 : 0;  // 16-step warmup: weight < e^-16 ~ 1e-7
  int tend = t0 + 32;                   // (tend - tstart) is 32 or 48: even
  const size_t bT = (size_t)b * T;
  const int kvoff = (g << 9) + (c0 << 1);  // [half][c][k|v] in shorts

  auto kvload = [&](int tt) {
    int tok = tr ? (((tt & 63) << 6) | (tt >> 6)) : tt;
    return *(const u16x4*)(kvb + (bT + tok) * 1024 + kvoff);
  };
  auto srload = [&](int tt) {
    return *(const u16x2*)(srb + (bT + tt) * 256 + c0);
  };

  // pipeline prologue: 2 iterations in flight
  u16x4 kvA = kvload(tstart);
  u16x4 kvB = kvload(tstart + 1);
  u16x2 svA = srload(tstart);
  u16x2 svB = srload(tstart + 1);

  for (int tt = tstart; tt < tend; tt += 2) {
    // prefetch tt+2 / tt+3 (clamped: last iter re-reads tend-1, harmless)
    int tp2 = tt + 2 < tend ? tt + 2 : tend - 1;
    int tp3 = tt + 3 < tend ? tt + 3 : tend - 1;
    u16x4 kvC = kvload(tp2);
    u16x4 kvD = kvload(tp3);
    u16x2 svC = srload(tp2);
    u16x2 svD = srload(tp3);

#pragma unroll
    for (int u = 0; u < 2; ++u) {
      int ti = tt + u;
      u16x4 kv4 = u ? kvB : kvA;
      u16x2 sv = u ? svB : svA;
      float k0 = bf2f(kv4[0]), v0 = bf2f(kv4[1]);
      float k1 = bf2f(kv4[2]), v1 = bf2f(kv4[3]);
      float e0 = __expf(k0), e1 = __expf(k1);
      if (ti >= t0) {
        float t0e = e0 * eu0, t1e = e1 * eu1;
        float y0 = fmaf(t0e, v0, P0) * __builtin_amdgcn_rcpf(Q0 + t0e);
        float y1 = fmaf(t1e, v1, P1) * __builtin_amdgcn_rcpf(Q1 + t1e);
        u16x2 ow;
        ow[0] = f2bf(y0 * bf2f(sv[0]));
        ow[1] = f2bf(y1 * bf2f(sv[1]));
        *(u16x2*)(xssr + (bT + ti) * 1024 + scol + c0) = ow;
      }
      P0 = fmaf(P0, D0, e0 * v0);
      Q0 = fmaf(Q0, D0, e0);
      P1 = fmaf(P1, D1, e1 * v1);
      Q1 = fmaf(Q1, D1, e1);
    }
    kvA = kvC; kvB = kvD;
    svA = svC; svB = svD;
  }
}

// ---------------- launch ----------------
extern "C" void kernel_launch(void* const* d_in, const int* in_sizes, int n_in,
                              void* d_out, int out_size, void* d_ws, size_t ws_size,
                              hipStream_t stream) {
  const float* x      = (const float*)d_in[0];
  const float* alpha  = (const float*)d_in[1];
  const float* dw1    = (const float*)d_in[2];
  const float* dw3    = (const float*)d_in[3];
  const float* dw5    = (const float*)d_in[4];
  const float* Wk     = (const float*)d_in[5];
  const float* Wv     = (const float*)d_in[6];
  const float* Wr     = (const float*)d_in[7];
  const float* Wf     = (const float*)d_in[8];
  const float* bfv    = (const float*)d_in[9];
  const float* Wb     = (const float*)d_in[10];
  const float* bbv    = (const float*)d_in[11];
  const float* sdecay = (const float*)d_in[12];
  const float* sfirst = (const float*)d_in[13];
  const float* Wo     = (const float*)d_in[14];
  (void)n_in; (void)out_size; (void)ws_size;

  const int Bn = in_sizes[0] / (4096 * 256);  // 8
  const int MT = Bn * 4096;                    // 32768

  char* ws = (char*)d_ws;
  size_t off = 0;
  auto alloc = [&](size_t bytes) {
    void* p = ws + off;
    off += (bytes + 255) & ~(size_t)255;
    return p;
  };
  short* xf            = (short*)alloc((size_t)MT * 256 * 2);
  unsigned short* kv   = (unsigned short*)alloc((size_t)MT * 1024 * 2);
  unsigned short* srb  = (unsigned short*)alloc((size_t)MT * 256 * 2);
  unsigned short* xssr = (unsigned short*)alloc((size_t)MT * 1024 * 2);
  short* wcat          = (short*)alloc((size_t)1280 * 256 * 2);
  float* bias          = (float*)alloc(1280 * 4);
  float* weff          = (float*)alloc(25 * 256 * 4);
  short* wob           = (short*)alloc((size_t)256 * 1024 * 2);

  k_weff<<<25, 256, 0, stream>>>(alpha, dw1, dw3, dw5, weff);
  k_combine<<<1280, 256, 0, stream>>>(Wk, Wv, Wr, Wf, Wb, bfv, bbv, wcat, bias);
  k_wo<<<1024, 256, 0, stream>>>(Wo, wob);
  k_shift<<<dim3(8, 32, Bn), 256, 0, stream>>>(x, weff, (unsigned short*)xf);
  // gemm1: 256x128 tile, 8 waves, 1280 blocks (3/CU), XCD A-locality NT=10.
  k_gemm1b<<<MT / 256 * 10, 512, 0, stream>>>(xf, wcat, bias, kv, srb, MT);
  k_wkv<<<dim3(128, 2, Bn), 256, 0, stream>>>(kv, srb, sdecay, sfirst, xssr);
  // gemm2: deep pipe (NK=16), natural grid, 3 blocks/CU (R4 exact).
  gemm_db<1, 64, 64><<<dim3(MT / 64, 2), 256, 0, stream>>>(
      (const short*)xssr, wob, nullptr, d_out, nullptr, MT, 256, 1024);
}

// Round 9
// 210.822 us; speedup vs baseline: 1.5703x; 1.5703x over previous
//
#include <hip/hip_runtime.h>

typedef __attribute__((ext_vector_type(8))) short bf16x8;
typedef __attribute__((ext_vector_type(4))) float f32x4;
typedef __attribute__((ext_vector_type(4))) unsigned short u16x4;
typedef __attribute__((ext_vector_type(2))) unsigned short u16x2;
typedef __attribute__((ext_vector_type(8))) unsigned short u16x8;

#define GLD16(g, l) __builtin_amdgcn_global_load_lds( \
    (const __attribute__((address_space(1))) void*)(g), \
    (__attribute__((address_space(3))) void*)(l), 16, 0, 0)

__device__ __forceinline__ unsigned short f2bf(float f) {
  unsigned u = __float_as_uint(f);
  unsigned r = u + 0x7FFFu + ((u >> 16) & 1u);
  return (unsigned short)(r >> 16);
}
__device__ __forceinline__ float bf2f(unsigned short h) {
  return __uint_as_float(((unsigned)h) << 16);
}

template <int N>
__device__ __forceinline__ void wait_vm() {
  if constexpr (N == 0) asm volatile("s_waitcnt vmcnt(0)" ::: "memory");
  else if constexpr (N == 6) asm volatile("s_waitcnt vmcnt(6)" ::: "memory");
  else static_assert(N == 0, "unsupported vmcnt");
}

// ---------------- prep kernels ----------------

__global__ void k_weff(const float* __restrict__ alpha,
                       const float* __restrict__ dw1,
                       const float* __restrict__ dw3,
                       const float* __restrict__ dw5,
                       float* __restrict__ weff) {
  int tap = blockIdx.x;        // 0..24
  int c = threadIdx.x;         // 0..255
  int dy = tap / 5, dx = tap % 5;
  float v = alpha[3] * dw5[c * 25 + tap];
  if (dy >= 1 && dy <= 3 && dx >= 1 && dx <= 3)
    v += alpha[2] * dw3[c * 9 + (dy - 1) * 3 + (dx - 1)];
  if (tap == 12) v += alpha[1] * dw1[c] + alpha[0];
  weff[tap * 256 + c] = v;
}

// combined weights with INTERLEAVED kv row order (R14-verified harmless, kept).
// Row map: k1[c]->2c, v1[c]->2c+1, k3[c]->512+2c, v3[c]->512+2c+1, Wr[c]->1024+c.
__global__ void k_combine(const float* __restrict__ Wk,
                          const float* __restrict__ Wv,
                          const float* __restrict__ Wr,
                          const float* __restrict__ Wf,
                          const float* __restrict__ Wb,
                          const float* __restrict__ bfv,
                          const float* __restrict__ bbv,
                          short* __restrict__ wcat,
                          float* __restrict__ bias) {
  int mat = blockIdx.x >> 8;   // 0:k1 1:k3 2:v1 3:v3 4:r
  int i = blockIdx.x & 255;
  int j = threadIdx.x;
  if (mat == 4) {
    wcat[(size_t)(1024 + i) * 256 + j] = (short)f2bf(Wr[i * 256 + j]);
    if (j == 0) bias[1024 + i] = 0.f;
    return;
  }
  const float* Am = (mat & 1) ? Wb : Wf;
  const float* Bm = (mat < 2) ? Wk : Wv;
  const float* arow = Am + i * 256;
  float acc = 0.f;
  for (int m = 0; m < 256; ++m) acc += arow[m] * Bm[m * 256 + j];
  int newrow = ((mat & 1) << 9) + (i << 1) + (mat >> 1);  // interleaved position
  wcat[(size_t)newrow * 256 + j] = (short)f2bf(acc);
  if (j == 0) bias[newrow] = (mat & 1) ? bbv[i] : bfv[i];
}

__global__ void k_wo(const float* __restrict__ Wo, short* __restrict__ wob) {
  int i = blockIdx.x * 256 + threadIdx.x;
  wob[i] = (short)f2bf(Wo[i]);
}

// ---------------- OmniShift: 2-row register sliding-window 5x5 stencil ----------
// R13-verified: w-tile 8, grid (8,32,B) = 2048 blocks = 8 blocks/CU, 32 waves/CU.
__global__ __launch_bounds__(256, 8)
void k_shift(const float* __restrict__ x, const float* __restrict__ weff,
             unsigned short* __restrict__ xf) {
  int c = threadIdx.x;
  int w0 = blockIdx.x * 8;    // 0,8,...,56
  int h0 = blockIdx.y * 2;    // 0..62
  int b = blockIdx.z;

  float wg[5][5];
#pragma unroll
  for (int dy = 0; dy < 5; ++dy)
#pragma unroll
    for (int dx = 0; dx < 5; ++dx)
      wg[dy][dx] = weff[(dy * 5 + dx) * 256 + c];

  const float* xb = x + (size_t)b * 4096 * 256 + c;
  int rowoff[6];
  bool rv[6];
#pragma unroll
  for (int r = 0; r < 6; ++r) {
    int y = h0 + r - 2;
    rv[r] = (y >= 0 && y < 64);
    int yc = y < 0 ? 0 : (y > 63 ? 63 : y);
    rowoff[r] = yc * 64 * 256;
  }

  float win[6][8];
#pragma unroll
  for (int j = -2; j <= 1; ++j) {
    int xx = w0 + j;
    int slot = j & 7;                 // w0 % 8 == 0 -> static
    bool xv = (xx >= 0);
    int xc = xx < 0 ? 0 : xx;
#pragma unroll
    for (int r = 0; r < 6; ++r) {
      float v = xb[rowoff[r] + xc * 256];
      win[r][slot] = (xv && rv[r]) ? v : 0.f;
    }
  }

  unsigned short* xo = xf + ((size_t)b * 4096 + (size_t)h0 * 64) * 256 + c;
#pragma unroll
  for (int ui = 0; ui < 8; ++ui) {
    int w = w0 + ui;
    {
      int xx = w + 2;
      int slot = (ui + 2) & 7;        // static
      bool xv = (xx < 64);
      int xc = xx > 63 ? 63 : xx;
#pragma unroll
      for (int r = 0; r < 6; ++r) {
        float v = xb[rowoff[r] + xc * 256];
        win[r][slot] = (xv && rv[r]) ? v : 0.f;
      }
    }
#pragma unroll
    for (int j = 0; j < 2; ++j) {
      float a0 = 0.f, a1 = 0.f, a2 = 0.f, a3 = 0.f, a4 = 0.f;
#pragma unroll
      for (int dx = 0; dx < 5; ++dx) {
        int slot = (ui - 2 + dx) & 7; // static
        a0 = fmaf(win[j + 0][slot], wg[0][dx], a0);
        a1 = fmaf(win[j + 1][slot], wg[1][dx], a1);
        a2 = fmaf(win[j + 2][slot], wg[2][dx], a2);
        a3 = fmaf(win[j + 3][slot], wg[3][dx], a3);
        a4 = fmaf(win[j + 4][slot], wg[4][dx], a4);
      }
      xo[((size_t)j * 64 + w) * 256] = f2bf(((a0 + a1) + (a2 + a3)) + a4);
    }
  }
}

// ---------------- gemm1: 128-m x 2x128-n per block, A-reuse (R24) ---------------
// out = xf[32768][256] @ wcat[1280][256]^T -> kv (bf16) / srb (sigmoid bf16).
// R8 insight: gemm2 (16 K-steps/block) runs ~900 TF; gemm1 (4 K-steps) 413 TF --
// fixed costs (cold stage, epilogue, barriers) dominate at small K-work/block.
// R24: TWO n-tiles per block sharing the staged A-tile. Per K-step: stage
// A 16KB + B-pair 32KB (48 KB LDS single-buffer) -> 128 MFMA per barrier pair
// (2x), A staged 5x not 10x, 1280 blocks (half the pro/epilogues).
// __launch_bounds__(256,3): the PROVEN-SAFE bound (gemm2: VGPR 88, no spill);
// R5/R8 lesson: (256,5) and (512,*) bounds starve the allocator -> 10x spill.
// acc[2][4][4]=128 regs fits the unified file at 3 waves/SIMD (cap ~680).
// BK=64 8-chunk XOR swizzle (0 conflicts; R7: BK=32's 4-chunk collides).
// XCD A-locality (R3-verified): xcd=bid&7 owns 32 contiguous m-tiles, 5 n-pairs
// temporally adjacent -> A re-reads hit own-XCD L2.
__global__ __launch_bounds__(256, 3)
void k_gemm1c(const short* __restrict__ A, const short* __restrict__ Bm,
              const float* __restrict__ bias,
              unsigned short* __restrict__ kv, unsigned short* __restrict__ srb,
              int M) {
  constexpr int BK = 64;
  constexpr int AE = 128 * BK;             // 8192 shorts = 16 KB
  constexpr int RW = 132;                  // padded epilogue row width (f32)
  __shared__ __align__(16) short lds[AE + 256 * BK];   // 16 + 32 = 48 KB

  int t = threadIdx.x;
  int lane = t & 63, wv = t >> 6;
  int wr = wv >> 1, wc = wv & 1;
  int x = blockIdx.x & 7;
  int j = blockIdx.x >> 3;                 // 0..159
  int mpx = M / (128 * 8);                 // m-tiles per XCD (32)
  int m0 = (x * mpx + j / 5) * 128;
  int nb = (j % 5) * 256;                  // n-pair base: 0,256,512,768,1024
  f32x4 acc[2][4][4] = {};

  float bb[2][4];
#pragma unroll
  for (int nt = 0; nt < 2; ++nt)
#pragma unroll
    for (int ni = 0; ni < 4; ++ni)
      bb[nt][ni] = bias[nb + nt * 128 + wc * 64 + ni * 16 + (lane & 15)];

  for (int k0 = 0; k0 < 256; k0 += BK) {
    // STAGE: linear LDS dest, XOR-swizzled global source chunk
#pragma unroll
    for (int i = 0; i < 4; ++i) {
      int cc = t + i * 256;
      int row = cc >> 3, kc = cc & 7;
      GLD16(A + (size_t)(m0 + row) * 256 + k0 + ((kc ^ (row & 7)) << 3), &lds[cc * 8]);
    }
#pragma unroll
    for (int i = 0; i < 8; ++i) {          // 256 B rows (both n-tiles)
      int cc = t + i * 256;
      int row = cc >> 3, kc = cc & 7;
      GLD16(Bm + (size_t)(nb + row) * 256 + k0 + ((kc ^ (row & 7)) << 3), &lds[AE + cc * 8]);
    }
    __syncthreads();
#pragma unroll
    for (int kk = 0; kk < 2; ++kk) {
      int ch = kk * 4 + (lane >> 4);
      bf16x8 av[4], bv[2][4];
#pragma unroll
      for (int i = 0; i < 4; ++i) {
        int row = wr * 64 + i * 16 + (lane & 15);
        av[i] = *(const bf16x8*)&lds[row * BK + ((ch ^ (row & 7)) << 3)];
      }
#pragma unroll
      for (int nt = 0; nt < 2; ++nt)
#pragma unroll
        for (int i = 0; i < 4; ++i) {
          int row = nt * 128 + wc * 64 + i * 16 + (lane & 15);
          bv[nt][i] = *(const bf16x8*)&lds[AE + row * BK + ((ch ^ (row & 7)) << 3)];
        }
#pragma unroll
      for (int nt = 0; nt < 2; ++nt)
#pragma unroll
        for (int mi = 0; mi < 4; ++mi)
#pragma unroll
          for (int ni = 0; ni < 4; ++ni)
            acc[nt][mi][ni] = __builtin_amdgcn_mfma_f32_16x16x32_bf16(
                av[mi], bv[nt][ni], acc[nt][mi][ni], 0, 0, 0);
    }
    __syncthreads();
  }

  // ---- epilogue: per n-tile, per mi: LDS transpose -> coalesced wide stores ----
  // Same verified 0-conflict row-major fl pattern; fl aliases lds (all K-loop
  // ds_reads drained by the final __syncthreads above).
  float* fl = (float*)lds;   // [32][RW] f32 = 16.9 KB < 48 KB
  int rrow = t >> 3;               // 0..31
  int colb = (t & 7) * 16;
  bool first = true;
#pragma unroll
  for (int nt = 0; nt < 2; ++nt) {
    int n0 = nb + nt * 128;
#pragma unroll
    for (int mi = 0; mi < 4; ++mi) {
      if (!first) __syncthreads();   // previous readout done before overwrite
      first = false;
      {
        int r0 = (lane >> 4) * 4;
#pragma unroll
        for (int ni = 0; ni < 4; ++ni) {
          int colL = wc * 64 + (lane & 15) + ni * 16;
          f32x4 v = acc[nt][mi][ni];
#pragma unroll
          for (int jj = 0; jj < 4; ++jj)
            fl[(wr * 16 + r0 + jj) * RW + colL] = v[jj] + bb[nt][ni];
        }
      }
      __syncthreads();
      float vv[16];
#pragma unroll
      for (int q = 0; q < 4; ++q)
        *(f32x4*)&vv[q * 4] = *(const f32x4*)&fl[rrow * RW + colb + q * 4];
      int grow = m0 + (rrow >> 4) * 64 + mi * 16 + (rrow & 15);
      u16x8 o0, o1;
      if (n0 < 1024) {
#pragma unroll
        for (int q = 0; q < 8; ++q) { o0[q] = f2bf(vv[q]); o1[q] = f2bf(vv[8 + q]); }
        unsigned short* dst = kv + (size_t)grow * 1024 + n0 + colb;
        *(u16x8*)dst = o0;
        *(u16x8*)(dst + 8) = o1;
      } else {
#pragma unroll
        for (int q = 0; q < 8; ++q) {
          o0[q] = f2bf(1.f / (1.f + __expf(-vv[q])));
          o1[q] = f2bf(1.f / (1.f + __expf(-vv[8 + q])));
        }
        unsigned short* dst = srb + (size_t)grow * 256 + (n0 - 1024) + colb;
        *(u16x8*)dst = o0;
        *(u16x8*)(dst + 8) = o1;
      }
    }
  }
}

// ---------------- gemm2: double-buffered deep pipeline (R4 exact) ---------------
// R4-verified ~19 us (~900 TF): BM=64/BK=64, NK=16, depth-2 counted-vmcnt
// pipeline, 3 blocks/CU, natural dim3(M/64, 2) grid (R5: XCD remap hurt here).
// Per iter: wait vmcnt(LD) (current step's loads; next step's stay in flight
// ACROSS the barrier), s_barrier, compute, lgkmcnt(0)+s_barrier, stage k+2.
// NEVER __syncthreads in the K-loop (drains vmcnt(0), kills the pipe).
template <int EPI, int BM, int BK>
__global__ __launch_bounds__(256, 3)
void gemm_db(const short* __restrict__ A, const short* __restrict__ Bm,
             const float* __restrict__ bias,
             void* __restrict__ O0, void* __restrict__ O1,
             int M, int N, int K) {
  constexpr int AE = BM * BK;           // shorts in A region of one buffer
  constexpr int BUFS = (BM + 128) * BK; // shorts per buffer
  constexpr int MI = BM / 32;           // m-fragments per wave
  constexpr int CH = BK / 8;            // 16B chunks per row
  constexpr int LA = BM * BK / 2048;    // A gld_lds per thread per step
  constexpr int LB = BK / 16;           // B gld_lds per thread per step
  constexpr int LD = LA + LB;           // loads in flight per step
  constexpr int RW = 132;               // padded row width for epilogue (f32)
  __shared__ __align__(16) short lds[2 * BUFS];

  int t = threadIdx.x;
  int lane = t & 63, wv = t >> 6;
  int wr = wv >> 1, wc = wv & 1;
  int m0 = blockIdx.x * BM, n0 = blockIdx.y * 128;
  const int NK = K / BK;
  f32x4 acc[MI][4] = {};

  float bb[4];
  if (EPI == 0) {
#pragma unroll
    for (int ni = 0; ni < 4; ++ni)
      bb[ni] = bias[n0 + wc * 64 + ni * 16 + (lane & 15)];
  }

  auto STAGE = [&](int step, int bo) {
    int k0 = step * BK;
#pragma unroll
    for (int i = 0; i < LA; ++i) {
      int cc = t + i * 256;
      int row = cc / CH, kc = cc % CH;
      GLD16(A + (size_t)(m0 + row) * K + k0 + ((kc ^ (row & (CH - 1))) << 3),
            &lds[bo + cc * 8]);
    }
#pragma unroll
    for (int i = 0; i < LB; ++i) {
      int cc = t + i * 256;
      int row = cc / CH, kc = cc % CH;
      GLD16(Bm + (size_t)(n0 + row) * K + k0 + ((kc ^ (row & (CH - 1))) << 3),
            &lds[bo + AE + cc * 8]);
    }
  };
  auto COMPUTE = [&](int bo) {
#pragma unroll
    for (int kk = 0; kk < BK / 32; ++kk) {
      int ch = kk * 4 + (lane >> 4);
      bf16x8 av[MI], bv[4];
#pragma unroll
      for (int i = 0; i < MI; ++i) {
        int row = wr * (BM / 2) + i * 16 + (lane & 15);
        av[i] = *(const bf16x8*)&lds[bo + row * BK + ((ch ^ (row & (CH - 1))) << 3)];
      }
#pragma unroll
      for (int i = 0; i < 4; ++i) {
        int row = wc * 64 + i * 16 + (lane & 15);
        bv[i] = *(const bf16x8*)&lds[bo + AE + row * BK + ((ch ^ (row & (CH - 1))) << 3)];
      }
#pragma unroll
      for (int mi = 0; mi < MI; ++mi)
#pragma unroll
        for (int ni = 0; ni < 4; ++ni)
          acc[mi][ni] = __builtin_amdgcn_mfma_f32_16x16x32_bf16(av[mi], bv[ni], acc[mi][ni], 0, 0, 0);
    }
  };

  STAGE(0, 0);
  STAGE(1, BUFS);
#pragma unroll
  for (int k = 0; k < 16; ++k) {      // bounded by max NK; break inside
    if (k >= NK) break;
    int bo = (k & 1) ? BUFS : 0;
    if (k < NK - 1) wait_vm<LD>();
    else wait_vm<0>();
    __builtin_amdgcn_s_barrier();
    COMPUTE(bo);
    asm volatile("s_waitcnt lgkmcnt(0)" ::: "memory");
    __builtin_amdgcn_s_barrier();
    if (k + 2 < NK) STAGE(k + 2, bo);
  }

  // ---- epilogue: LDS transpose (row-major fl) -> coalesced wide stores ----
  float* fl = (float*)lds;   // [32 rows][RW cols] f32 = 16.9 KB
  int rrow = t >> 3;               // 0..31
  int colb = (t & 7) * 16;
#pragma unroll
  for (int mi = 0; mi < MI; ++mi) {
    if (mi) __syncthreads();       // previous readout done before overwrite
    {
      int r0 = (lane >> 4) * 4;
#pragma unroll
      for (int ni = 0; ni < 4; ++ni) {
        int colL = wc * 64 + (lane & 15) + ni * 16;
        f32x4 v = acc[mi][ni];
#pragma unroll
        for (int j = 0; j < 4; ++j) {
          float vj = v[j];
          if (EPI == 0) vj += bb[ni];
          fl[(wr * 16 + r0 + j) * RW + colL] = vj;
        }
      }
    }
    __syncthreads();
    float vv[16];
#pragma unroll
    for (int q = 0; q < 4; ++q)
      *(f32x4*)&vv[q * 4] = *(const f32x4*)&fl[rrow * RW + colb + q * 4];
    int grow = m0 + (rrow >> 4) * (BM / 2) + mi * 16 + (rrow & 15);
    if (EPI == 0) {
      u16x8 o0, o1;
      if (n0 < 1024) {
#pragma unroll
        for (int q = 0; q < 8; ++q) { o0[q] = f2bf(vv[q]); o1[q] = f2bf(vv[8 + q]); }
        unsigned short* dst = (unsigned short*)O0 + (size_t)grow * 1024 + n0 + colb;
        *(u16x8*)dst = o0;
        *(u16x8*)(dst + 8) = o1;
      } else {
#pragma unroll
        for (int q = 0; q < 8; ++q) {
          o0[q] = f2bf(1.f / (1.f + __expf(-vv[q])));
          o1[q] = f2bf(1.f / (1.f + __expf(-vv[8 + q])));
        }
        unsigned short* dst = (unsigned short*)O1 + (size_t)grow * 256 + (n0 - 1024) + colb;
        *(u16x8*)dst = o0;
        *(u16x8*)(dst + 8) = o1;
      }
    } else {
      float* dst = (float*)O0 + (size_t)grow * N + n0 + colb;
#pragma unroll
      for (int q = 0; q < 4; ++q) {
        f32x4 ov = {vv[q * 4], vv[q * 4 + 1], vv[q * 4 + 2], vv[q * 4 + 3]};
        *(f32x4*)(dst + q * 4) = ov;
      }
    }
  }
}

// ---------------- WKV (software-pipelined; 2 ch/thread, interleaved kv) ---------
// R15-verified: explicit x2-unroll prefetch pipeline (4-6 outstanding loads/wave).
// grid 128 x 2(tr) x 8 = 2048 blocks; chunk 32, warmup 16.
__global__ __launch_bounds__(256, 8)
void k_wkv(const unsigned short* __restrict__ kvb, const unsigned short* __restrict__ srb,
           const float* __restrict__ decay, const float* __restrict__ first,
           unsigned short* __restrict__ xssr) {
  const int T = 4096;
  int tid = threadIdx.x;
  int g = tid >> 7;              // 0: k1/v1 half, 1: k3/v3 half
  int l = tid & 127;
  int c0 = l * 2;
  int tr = blockIdx.y;           // 0 natural, 1 transposed scan order
  int s = (g << 1) | tr;         // stream in concat order k1,k2,k3,k4
  int scol = s * 256;
  int chunk = blockIdx.x;        // 0..127, 32 tokens each
  int b = blockIdx.z;
  const float invT = 1.0f / 4096.0f;

  float P0 = 0.f, P1 = 0.f, Q0 = 0.f, Q1 = 0.f;
  float D0 = __expf(-__expf(decay[scol + c0] * invT));
  float D1 = __expf(-__expf(decay[scol + c0 + 1] * invT));
  float eu0 = __expf(first[scol + c0] * invT);
  float eu1 = __expf(first[scol + c0 + 1] * invT);

  int t0 = chunk * 32;
  int tstart = t0 >= 16 ? t0 - 16 : 0;  // 16-step warmup: weight < e^-16 ~ 1e-7
  int tend = t0 + 32;                   // (tend - tstart) is 32 or 48: even
  const size_t bT = (size_t)b * T;
  const int kvoff = (g << 9) + (c0 << 1);  // [half][c][k|v] in shorts

  auto kvload = [&](int tt) {
    int tok = tr ? (((tt & 63) << 6) | (tt >> 6)) : tt;
    return *(const u16x4*)(kvb + (bT + tok) * 1024 + kvoff);
  };
  auto srload = [&](int tt) {
    return *(const u16x2*)(srb + (bT + tt) * 256 + c0);
  };

  // pipeline prologue: 2 iterations in flight
  u16x4 kvA = kvload(tstart);
  u16x4 kvB = kvload(tstart + 1);
  u16x2 svA = srload(tstart);
  u16x2 svB = srload(tstart + 1);

  for (int tt = tstart; tt < tend; tt += 2) {
    // prefetch tt+2 / tt+3 (clamped: last iter re-reads tend-1, harmless)
    int tp2 = tt + 2 < tend ? tt + 2 : tend - 1;
    int tp3 = tt + 3 < tend ? tt + 3 : tend - 1;
    u16x4 kvC = kvload(tp2);
    u16x4 kvD = kvload(tp3);
    u16x2 svC = srload(tp2);
    u16x2 svD = srload(tp3);

#pragma unroll
    for (int u = 0; u < 2; ++u) {
      int ti = tt + u;
      u16x4 kv4 = u ? kvB : kvA;
      u16x2 sv = u ? svB : svA;
      float k0 = bf2f(kv4[0]), v0 = bf2f(kv4[1]);
      float k1 = bf2f(kv4[2]), v1 = bf2f(kv4[3]);
      float e0 = __expf(k0), e1 = __expf(k1);
      if (ti >= t0) {
        float t0e = e0 * eu0, t1e = e1 * eu1;
        float y0 = fmaf(t0e, v0, P0) * __builtin_amdgcn_rcpf(Q0 + t0e);
        float y1 = fmaf(t1e, v1, P1) * __builtin_amdgcn_rcpf(Q1 + t1e);
        u16x2 ow;
        ow[0] = f2bf(y0 * bf2f(sv[0]));
        ow[1] = f2bf(y1 * bf2f(sv[1]));
        *(u16x2*)(xssr + (bT + ti) * 1024 + scol + c0) = ow;
      }
      P0 = fmaf(P0, D0, e0 * v0);
      Q0 = fmaf(Q0, D0, e0);
      P1 = fmaf(P1, D1, e1 * v1);
      Q1 = fmaf(Q1, D1, e1);
    }
    kvA = kvC; kvB = kvD;
    svA = svC; svB = svD;
  }
}

// ---------------- launch ----------------
extern "C" void kernel_launch(void* const* d_in, const int* in_sizes, int n_in,
                              void* d_out, int out_size, void* d_ws, size_t ws_size,
                              hipStream_t stream) {
  const float* x      = (const float*)d_in[0];
  const float* alpha  = (const float*)d_in[1];
  const float* dw1    = (const float*)d_in[2];
  const float* dw3    = (const float*)d_in[3];
  const float* dw5    = (const float*)d_in[4];
  const float* Wk     = (const float*)d_in[5];
  const float* Wv     = (const float*)d_in[6];
  const float* Wr     = (const float*)d_in[7];
  const float* Wf     = (const float*)d_in[8];
  const float* bfv    = (const float*)d_in[9];
  const float* Wb     = (const float*)d_in[10];
  const float* bbv    = (const float*)d_in[11];
  const float* sdecay = (const float*)d_in[12];
  const float* sfirst = (const float*)d_in[13];
  const float* Wo     = (const float*)d_in[14];
  (void)n_in; (void)out_size; (void)ws_size;

  const int Bn = in_sizes[0] / (4096 * 256);  // 8
  const int MT = Bn * 4096;                    // 32768

  char* ws = (char*)d_ws;
  size_t off = 0;
  auto alloc = [&](size_t bytes) {
    void* p = ws + off;
    off += (bytes + 255) & ~(size_t)255;
    return p;
  };
  short* xf            = (short*)alloc((size_t)MT * 256 * 2);
  unsigned short* kv   = (unsigned short*)alloc((size_t)MT * 1024 * 2);
  unsigned short* srb  = (unsigned short*)alloc((size_t)MT * 256 * 2);
  unsigned short* xssr = (unsigned short*)alloc((size_t)MT * 1024 * 2);
  short* wcat          = (short*)alloc((size_t)1280 * 256 * 2);
  float* bias          = (float*)alloc(1280 * 4);
  float* weff          = (float*)alloc(25 * 256 * 4);
  short* wob           = (short*)alloc((size_t)256 * 1024 * 2);

  k_weff<<<25, 256, 0, stream>>>(alpha, dw1, dw3, dw5, weff);
  k_combine<<<1280, 256, 0, stream>>>(Wk, Wv, Wr, Wf, Wb, bfv, bbv, wcat, bias);
  k_wo<<<1024, 256, 0, stream>>>(Wo, wob);
  k_shift<<<dim3(8, 32, Bn), 256, 0, stream>>>(x, weff, (unsigned short*)xf);
  // gemm1: 128m x 256n (2 n-tiles, A-reuse) per block, 1280 blocks, 3/CU,
  // XCD A-locality (5 n-pairs per m-tile adjacent per XCD).
  k_gemm1c<<<MT / 128 * 5, 256, 0, stream>>>(xf, wcat, bias, kv, srb, MT);
  k_wkv<<<dim3(128, 2, Bn), 256, 0, stream>>>(kv, srb, sdecay, sfirst, xssr);
  // gemm2: deep pipe (NK=16), natural grid, 3 blocks/CU (R4 exact).
  gemm_db<1, 64, 64><<<dim3(MT / 64, 2), 256, 0, stream>>>(
      (const short*)xssr, wob, nullptr, d_out, nullptr, MT, 256, 1024);
}

// Round 10
// 156.818 us; speedup vs baseline: 2.1111x; 1.3444x over previous
//
#include <hip/hip_runtime.h>

typedef __attribute__((ext_vector_type(8))) short bf16x8;
typedef __attribute__((ext_vector_type(4))) float f32x4;
typedef __attribute__((ext_vector_type(4))) unsigned short u16x4;
typedef __attribute__((ext_vector_type(2))) unsigned short u16x2;
typedef __attribute__((ext_vector_type(8))) unsigned short u16x8;

#define GLD16(g, l) __builtin_amdgcn_global_load_lds( \
    (const __attribute__((address_space(1))) void*)(g), \
    (__attribute__((address_space(3))) void*)(l), 16, 0, 0)

__device__ __forceinline__ unsigned short f2bf(float f) {
  unsigned u = __float_as_uint(f);
  unsigned r = u + 0x7FFFu + ((u >> 16) & 1u);
  return (unsigned short)(r >> 16);
}
__device__ __forceinline__ float bf2f(unsigned short h) {
  return __uint_as_float(((unsigned)h) << 16);
}

template <int N>
__device__ __forceinline__ void wait_vm() {
  if constexpr (N == 0) asm volatile("s_waitcnt vmcnt(0)" ::: "memory");
  else if constexpr (N == 6) asm volatile("s_waitcnt vmcnt(6)" ::: "memory");
  else static_assert(N == 0, "unsupported vmcnt");
}

// ---------------- prep kernels ----------------

__global__ void k_weff(const float* __restrict__ alpha,
                       const float* __restrict__ dw1,
                       const float* __restrict__ dw3,
                       const float* __restrict__ dw5,
                       float* __restrict__ weff) {
  int tap = blockIdx.x;        // 0..24
  int c = threadIdx.x;         // 0..255
  int dy = tap / 5, dx = tap % 5;
  float v = alpha[3] * dw5[c * 25 + tap];
  if (dy >= 1 && dy <= 3 && dx >= 1 && dx <= 3)
    v += alpha[2] * dw3[c * 9 + (dy - 1) * 3 + (dx - 1)];
  if (tap == 12) v += alpha[1] * dw1[c] + alpha[0];
  weff[tap * 256 + c] = v;
}

// combined weights with INTERLEAVED kv row order (R14-verified harmless, kept).
// Row map: k1[c]->2c, v1[c]->2c+1, k3[c]->512+2c, v3[c]->512+2c+1, Wr[c]->1024+c.
__global__ void k_combine(const float* __restrict__ Wk,
                          const float* __restrict__ Wv,
                          const float* __restrict__ Wr,
                          const float* __restrict__ Wf,
                          const float* __restrict__ Wb,
                          const float* __restrict__ bfv,
                          const float* __restrict__ bbv,
                          short* __restrict__ wcat,
                          float* __restrict__ bias) {
  int mat = blockIdx.x >> 8;   // 0:k1 1:k3 2:v1 3:v3 4:r
  int i = blockIdx.x & 255;
  int j = threadIdx.x;
  if (mat == 4) {
    wcat[(size_t)(1024 + i) * 256 + j] = (short)f2bf(Wr[i * 256 + j]);
    if (j == 0) bias[1024 + i] = 0.f;
    return;
  }
  const float* Am = (mat & 1) ? Wb : Wf;
  const float* Bm = (mat < 2) ? Wk : Wv;
  const float* arow = Am + i * 256;
  float acc = 0.f;
  for (int m = 0; m < 256; ++m) acc += arow[m] * Bm[m * 256 + j];
  int newrow = ((mat & 1) << 9) + (i << 1) + (mat >> 1);  // interleaved position
  wcat[(size_t)newrow * 256 + j] = (short)f2bf(acc);
  if (j == 0) bias[newrow] = (mat & 1) ? bbv[i] : bfv[i];
}

__global__ void k_wo(const float* __restrict__ Wo, short* __restrict__ wob) {
  int i = blockIdx.x * 256 + threadIdx.x;
  wob[i] = (short)f2bf(Wo[i]);
}

// ---------------- OmniShift: 2-row register sliding-window 5x5 stencil ----------
// R13-verified: w-tile 8, grid (8,32,B) = 2048 blocks = 8 blocks/CU, 32 waves/CU.
__global__ __launch_bounds__(256, 8)
void k_shift(const float* __restrict__ x, const float* __restrict__ weff,
             unsigned short* __restrict__ xf) {
  int c = threadIdx.x;
  int w0 = blockIdx.x * 8;    // 0,8,...,56
  int h0 = blockIdx.y * 2;    // 0..62
  int b = blockIdx.z;

  float wg[5][5];
#pragma unroll
  for (int dy = 0; dy < 5; ++dy)
#pragma unroll
    for (int dx = 0; dx < 5; ++dx)
      wg[dy][dx] = weff[(dy * 5 + dx) * 256 + c];

  const float* xb = x + (size_t)b * 4096 * 256 + c;
  int rowoff[6];
  bool rv[6];
#pragma unroll
  for (int r = 0; r < 6; ++r) {
    int y = h0 + r - 2;
    rv[r] = (y >= 0 && y < 64);
    int yc = y < 0 ? 0 : (y > 63 ? 63 : y);
    rowoff[r] = yc * 64 * 256;
  }

  float win[6][8];
#pragma unroll
  for (int j = -2; j <= 1; ++j) {
    int xx = w0 + j;
    int slot = j & 7;                 // w0 % 8 == 0 -> static
    bool xv = (xx >= 0);
    int xc = xx < 0 ? 0 : xx;
#pragma unroll
    for (int r = 0; r < 6; ++r) {
      float v = xb[rowoff[r] + xc * 256];
      win[r][slot] = (xv && rv[r]) ? v : 0.f;
    }
  }

  unsigned short* xo = xf + ((size_t)b * 4096 + (size_t)h0 * 64) * 256 + c;
#pragma unroll
  for (int ui = 0; ui < 8; ++ui) {
    int w = w0 + ui;
    {
      int xx = w + 2;
      int slot = (ui + 2) & 7;        // static
      bool xv = (xx < 64);
      int xc = xx > 63 ? 63 : xx;
#pragma unroll
      for (int r = 0; r < 6; ++r) {
        float v = xb[rowoff[r] + xc * 256];
        win[r][slot] = (xv && rv[r]) ? v : 0.f;
      }
    }
#pragma unroll
    for (int j = 0; j < 2; ++j) {
      float a0 = 0.f, a1 = 0.f, a2 = 0.f, a3 = 0.f, a4 = 0.f;
#pragma unroll
      for (int dx = 0; dx < 5; ++dx) {
        int slot = (ui - 2 + dx) & 7; // static
        a0 = fmaf(win[j + 0][slot], wg[0][dx], a0);
        a1 = fmaf(win[j + 1][slot], wg[1][dx], a1);
        a2 = fmaf(win[j + 2][slot], wg[2][dx], a2);
        a3 = fmaf(win[j + 3][slot], wg[3][dx], a3);
        a4 = fmaf(win[j + 4][slot], wg[4][dx], a4);
      }
      xo[((size_t)j * 64 + w) * 256] = f2bf(((a0 + a1) + (a2 + a3)) + a4);
    }
  }
}

// ---------------- gemm1: single-buffer bf16 MFMA GEMM (R6 exact, BEST) ----------
// out[M][N] = A[M][K] * B[N][K]^T. 128x128 tile, BK=64, 4 waves (2x2), 16x16x32.
// (256,4): VGPR 60, no spill. REGISTER WALL (R5/R8/R9): acc must stay <= 64 f32
// per thread -- (256,5), 512-thread, and 2-n-tile variants all spill 2-10x.
// This structure's ~52 us is its ceiling; do not grow work/block here.
// XOR swizzle on stage-source chunk + ds_read addr (0 conflicts, verified).
// NT>0: XCD A-locality flat grid (R19-verified: FETCH 27->14.5 MB, 60->52 us):
// xcd=bid&7 owns M/BM/8 contiguous m-tiles, NT n-tiles temporally adjacent.
template <int EPI, int BM, int BK, int NT>
__global__ __launch_bounds__(256, (BK == 128) ? 3 : 4)
void gemm_bt(const short* __restrict__ A, const short* __restrict__ Bm,
             const float* __restrict__ bias,
             void* __restrict__ O0, void* __restrict__ O1,
             int M, int N, int K) {
  constexpr int AE = BM * BK;          // shorts in A buffer
  constexpr int MI = BM / 32;          // m-fragments per wave
  constexpr int CH = BK / 8;           // 16B chunks per row
  constexpr int LA = BM * BK / 2048;   // A gld_lds per thread
  constexpr int LB = BK / 16;          // B gld_lds per thread
  constexpr int RW = 132;              // padded row width for epilogue (f32)
  __shared__ __align__(16) short lds[AE + 128 * BK];

  int t = threadIdx.x;
  int lane = t & 63, wv = t >> 6;
  int wr = wv >> 1, wc = wv & 1;
  int m0, n0;
  if (NT) {
    int x = blockIdx.x & 7;
    int j = blockIdx.x >> 3;
    int mpx = M / (BM * 8);            // m-tiles per XCD
    m0 = (x * mpx + j / NT) * BM;
    n0 = (j % NT) * 128;
  } else {
    m0 = blockIdx.x * BM;
    n0 = blockIdx.y * 128;
  }
  f32x4 acc[MI][4] = {};

  for (int k0 = 0; k0 < K; k0 += BK) {
    // STAGE: linear LDS dest, swizzled global source chunk
#pragma unroll
    for (int i = 0; i < LA; ++i) {
      int cc = t + i * 256;
      int row = cc / CH, kc = cc % CH;
      GLD16(A + (size_t)(m0 + row) * K + k0 + ((kc ^ (row & (CH - 1))) << 3), &lds[cc * 8]);
    }
#pragma unroll
    for (int i = 0; i < LB; ++i) {
      int cc = t + i * 256;
      int row = cc / CH, kc = cc % CH;
      GLD16(Bm + (size_t)(n0 + row) * K + k0 + ((kc ^ (row & (CH - 1))) << 3), &lds[AE + cc * 8]);
    }
    __syncthreads();
    // COMPUTE: same XOR on ds_read address
#pragma unroll
    for (int kk = 0; kk < BK / 32; ++kk) {
      int ch = kk * 4 + (lane >> 4);
      bf16x8 av[MI], bv[4];
#pragma unroll
      for (int i = 0; i < MI; ++i) {
        int row = wr * (BM / 2) + i * 16 + (lane & 15);
        av[i] = *(const bf16x8*)&lds[row * BK + ((ch ^ (row & (CH - 1))) << 3)];
      }
#pragma unroll
      for (int i = 0; i < 4; ++i) {
        int row = wc * 64 + i * 16 + (lane & 15);
        bv[i] = *(const bf16x8*)&lds[AE + row * BK + ((ch ^ (row & (CH - 1))) << 3)];
      }
#pragma unroll
      for (int mi = 0; mi < MI; ++mi)
#pragma unroll
        for (int ni = 0; ni < 4; ++ni)
          acc[mi][ni] = __builtin_amdgcn_mfma_f32_16x16x32_bf16(av[mi], bv[ni], acc[mi][ni], 0, 0, 0);
    }
    __syncthreads();
  }

  // ---- epilogue: LDS transpose (row-major fl) -> coalesced wide stores ----
  float* fl = (float*)lds;   // [32 rows][RW cols] f32 = 16.9 KB
  float bb[4];
  if (EPI == 0) {
#pragma unroll
    for (int ni = 0; ni < 4; ++ni)
      bb[ni] = bias[n0 + wc * 64 + ni * 16 + (lane & 15)];
  }
  int rrow = t >> 3;               // 0..31
  int colb = (t & 7) * 16;
#pragma unroll
  for (int mi = 0; mi < MI; ++mi) {
    if (mi) __syncthreads();       // previous readout done before overwrite
    {
      int r0 = (lane >> 4) * 4;
#pragma unroll
      for (int ni = 0; ni < 4; ++ni) {
        int colL = wc * 64 + (lane & 15) + ni * 16;
        f32x4 v = acc[mi][ni];
#pragma unroll
        for (int j = 0; j < 4; ++j) {
          float vj = v[j];
          if (EPI == 0) vj += bb[ni];
          fl[(wr * 16 + r0 + j) * RW + colL] = vj;
        }
      }
    }
    __syncthreads();
    float vv[16];
#pragma unroll
    for (int q = 0; q < 4; ++q)
      *(f32x4*)&vv[q * 4] = *(const f32x4*)&fl[rrow * RW + colb + q * 4];
    int grow = m0 + (rrow >> 4) * (BM / 2) + mi * 16 + (rrow & 15);
    if (EPI == 0) {
      u16x8 o0, o1;
      if (n0 < 1024) {
#pragma unroll
        for (int q = 0; q < 8; ++q) { o0[q] = f2bf(vv[q]); o1[q] = f2bf(vv[8 + q]); }
        unsigned short* dst = (unsigned short*)O0 + (size_t)grow * 1024 + n0 + colb;
        *(u16x8*)dst = o0;
        *(u16x8*)(dst + 8) = o1;
      } else {
#pragma unroll
        for (int q = 0; q < 8; ++q) {
          o0[q] = f2bf(1.f / (1.f + __expf(-vv[q])));
          o1[q] = f2bf(1.f / (1.f + __expf(-vv[8 + q])));
        }
        unsigned short* dst = (unsigned short*)O1 + (size_t)grow * 256 + (n0 - 1024) + colb;
        *(u16x8*)dst = o0;
        *(u16x8*)(dst + 8) = o1;
      }
    } else {
      float* dst = (float*)O0 + (size_t)grow * N + n0 + colb;
#pragma unroll
      for (int q = 0; q < 4; ++q) {
        f32x4 ov = {vv[q * 4], vv[q * 4 + 1], vv[q * 4 + 2], vv[q * 4 + 3]};
        *(f32x4*)(dst + q * 4) = ov;
      }
    }
  }
}

// ---------------- gemm2: double-buffered deep pipeline (R4 exact) ---------------
// R4-verified ~19 us (~900 TF): BM=64/BK=64, NK=16, depth-2 counted-vmcnt
// pipeline, 3 blocks/CU, natural dim3(M/64, 2) grid (R5: XCD remap hurt here).
// Per iter: wait vmcnt(LD) (current step's loads; next step's stay in flight
// ACROSS the barrier), s_barrier, compute, lgkmcnt(0)+s_barrier, stage k+2.
// NEVER __syncthreads in the K-loop (drains vmcnt(0), kills the pipe).
template <int EPI, int BM, int BK>
__global__ __launch_bounds__(256, 3)
void gemm_db(const short* __restrict__ A, const short* __restrict__ Bm,
             const float* __restrict__ bias,
             void* __restrict__ O0, void* __restrict__ O1,
             int M, int N, int K) {
  constexpr int AE = BM * BK;           // shorts in A region of one buffer
  constexpr int BUFS = (BM + 128) * BK; // shorts per buffer
  constexpr int MI = BM / 32;           // m-fragments per wave
  constexpr int CH = BK / 8;            // 16B chunks per row
  constexpr int LA = BM * BK / 2048;    // A gld_lds per thread per step
  constexpr int LB = BK / 16;           // B gld_lds per thread per step
  constexpr int LD = LA + LB;           // loads in flight per step
  constexpr int RW = 132;               // padded row width for epilogue (f32)
  __shared__ __align__(16) short lds[2 * BUFS];

  int t = threadIdx.x;
  int lane = t & 63, wv = t >> 6;
  int wr = wv >> 1, wc = wv & 1;
  int m0 = blockIdx.x * BM, n0 = blockIdx.y * 128;
  const int NK = K / BK;
  f32x4 acc[MI][4] = {};

  float bb[4];
  if (EPI == 0) {
#pragma unroll
    for (int ni = 0; ni < 4; ++ni)
      bb[ni] = bias[n0 + wc * 64 + ni * 16 + (lane & 15)];
  }

  auto STAGE = [&](int step, int bo) {
    int k0 = step * BK;
#pragma unroll
    for (int i = 0; i < LA; ++i) {
      int cc = t + i * 256;
      int row = cc / CH, kc = cc % CH;
      GLD16(A + (size_t)(m0 + row) * K + k0 + ((kc ^ (row & (CH - 1))) << 3),
            &lds[bo + cc * 8]);
    }
#pragma unroll
    for (int i = 0; i < LB; ++i) {
      int cc = t + i * 256;
      int row = cc / CH, kc = cc % CH;
      GLD16(Bm + (size_t)(n0 + row) * K + k0 + ((kc ^ (row & (CH - 1))) << 3),
            &lds[bo + AE + cc * 8]);
    }
  };
  auto COMPUTE = [&](int bo) {
#pragma unroll
    for (int kk = 0; kk < BK / 32; ++kk) {
      int ch = kk * 4 + (lane >> 4);
      bf16x8 av[MI], bv[4];
#pragma unroll
      for (int i = 0; i < MI; ++i) {
        int row = wr * (BM / 2) + i * 16 + (lane & 15);
        av[i] = *(const bf16x8*)&lds[bo + row * BK + ((ch ^ (row & (CH - 1))) << 3)];
      }
#pragma unroll
      for (int i = 0; i < 4; ++i) {
        int row = wc * 64 + i * 16 + (lane & 15);
        bv[i] = *(const bf16x8*)&lds[bo + AE + row * BK + ((ch ^ (row & (CH - 1))) << 3)];
      }
#pragma unroll
      for (int mi = 0; mi < MI; ++mi)
#pragma unroll
        for (int ni = 0; ni < 4; ++ni)
          acc[mi][ni] = __builtin_amdgcn_mfma_f32_16x16x32_bf16(av[mi], bv[ni], acc[mi][ni], 0, 0, 0);
    }
  };

  STAGE(0, 0);
  STAGE(1, BUFS);
#pragma unroll
  for (int k = 0; k < 16; ++k) {      // bounded by max NK; break inside
    if (k >= NK) break;
    int bo = (k & 1) ? BUFS : 0;
    if (k < NK - 1) wait_vm<LD>();
    else wait_vm<0>();
    __builtin_amdgcn_s_barrier();
    COMPUTE(bo);
    asm volatile("s_waitcnt lgkmcnt(0)" ::: "memory");
    __builtin_amdgcn_s_barrier();
    if (k + 2 < NK) STAGE(k + 2, bo);
  }

  // ---- epilogue: LDS transpose (row-major fl) -> coalesced wide stores ----
  float* fl = (float*)lds;   // [32 rows][RW cols] f32 = 16.9 KB
  int rrow = t >> 3;               // 0..31
  int colb = (t & 7) * 16;
#pragma unroll
  for (int mi = 0; mi < MI; ++mi) {
    if (mi) __syncthreads();       // previous readout done before overwrite
    {
      int r0 = (lane >> 4) * 4;
#pragma unroll
      for (int ni = 0; ni < 4; ++ni) {
        int colL = wc * 64 + (lane & 15) + ni * 16;
        f32x4 v = acc[mi][ni];
#pragma unroll
        for (int j = 0; j < 4; ++j) {
          float vj = v[j];
          if (EPI == 0) vj += bb[ni];
          fl[(wr * 16 + r0 + j) * RW + colL] = vj;
        }
      }
    }
    __syncthreads();
    float vv[16];
#pragma unroll
    for (int q = 0; q < 4; ++q)
      *(f32x4*)&vv[q * 4] = *(const f32x4*)&fl[rrow * RW + colb + q * 4];
    int grow = m0 + (rrow >> 4) * (BM / 2) + mi * 16 + (rrow & 15);
    if (EPI == 0) {
      u16x8 o0, o1;
      if (n0 < 1024) {
#pragma unroll
        for (int q = 0; q < 8; ++q) { o0[q] = f2bf(vv[q]); o1[q] = f2bf(vv[8 + q]); }
        unsigned short* dst = (unsigned short*)O0 + (size_t)grow * 1024 + n0 + colb;
        *(u16x8*)dst = o0;
        *(u16x8*)(dst + 8) = o1;
      } else {
#pragma unroll
        for (int q = 0; q < 8; ++q) {
          o0[q] = f2bf(1.f / (1.f + __expf(-vv[q])));
          o1[q] = f2bf(1.f / (1.f + __expf(-vv[8 + q])));
        }
        unsigned short* dst = (unsigned short*)O1 + (size_t)grow * 256 + (n0 - 1024) + colb;
        *(u16x8*)dst = o0;
        *(u16x8*)(dst + 8) = o1;
      }
    } else {
      float* dst = (float*)O0 + (size_t)grow * N + n0 + colb;
#pragma unroll
      for (int q = 0; q < 4; ++q) {
        f32x4 ov = {vv[q * 4], vv[q * 4 + 1], vv[q * 4 + 2], vv[q * 4 + 3]};
        *(f32x4*)(dst + q * 4) = ov;
      }
    }
  }
}

// ---------------- WKV (software-pipelined; 2 ch/thread, interleaved kv) ---------
// R15-verified prefetch pipeline (4-6 outstanding loads/wave).
// R25: chunk 32 -> 64. Warmup is 16 tokens regardless of chunk, so read+VALU
// amplification drops 48/32=1.5x -> 80/64=1.25x (-17% of wkv load volume).
// grid 64 x 2(tr) x 8 = 1024 blocks = 4/CU = 16 waves/CU (ample for mem-bound).
__global__ __launch_bounds__(256, 8)
void k_wkv(const unsigned short* __restrict__ kvb, const unsigned short* __restrict__ srb,
           const float* __restrict__ decay, const float* __restrict__ first,
           unsigned short* __restrict__ xssr) {
  const int T = 4096;
  int tid = threadIdx.x;
  int g = tid >> 7;              // 0: k1/v1 half, 1: k3/v3 half
  int l = tid & 127;
  int c0 = l * 2;
  int tr = blockIdx.y;           // 0 natural, 1 transposed scan order
  int s = (g << 1) | tr;         // stream in concat order k1,k2,k3,k4
  int scol = s * 256;
  int chunk = blockIdx.x;        // 0..63, 64 tokens each
  int b = blockIdx.z;
  const float invT = 1.0f / 4096.0f;

  float P0 = 0.f, P1 = 0.f, Q0 = 0.f, Q1 = 0.f;
  float D0 = __expf(-__expf(decay[scol + c0] * invT));
  float D1 = __expf(-__expf(decay[scol + c0 + 1] * invT));
  float eu0 = __expf(first[scol + c0] * invT);
  float eu1 = __expf(first[scol + c0 + 1] * invT);

  int t0 = chunk * 64;
  int tstart = t0 >= 16 ? t0 - 16 : 0;  // 16-step warmup: weight < e^-16 ~ 1e-7
  int tend = t0 + 64;                   // (tend - tstart) is 64 or 80: even
  const size_t bT = (size_t)b * T;
  const int kvoff = (g << 9) + (c0 << 1);  // [half][c][k|v] in shorts

  auto kvload = [&](int tt) {
    int tok = tr ? (((tt & 63) << 6) | (tt >> 6)) : tt;
    return *(const u16x4*)(kvb + (bT + tok) * 1024 + kvoff);
  };
  auto srload = [&](int tt) {
    return *(const u16x2*)(srb + (bT + tt) * 256 + c0);
  };

  // pipeline prologue: 2 iterations in flight
  u16x4 kvA = kvload(tstart);
  u16x4 kvB = kvload(tstart + 1);
  u16x2 svA = srload(tstart);
  u16x2 svB = srload(tstart + 1);

  for (int tt = tstart; tt < tend; tt += 2) {
    // prefetch tt+2 / tt+3 (clamped: last iter re-reads tend-1, harmless)
    int tp2 = tt + 2 < tend ? tt + 2 : tend - 1;
    int tp3 = tt + 3 < tend ? tt + 3 : tend - 1;
    u16x4 kvC = kvload(tp2);
    u16x4 kvD = kvload(tp3);
    u16x2 svC = srload(tp2);
    u16x2 svD = srload(tp3);

#pragma unroll
    for (int u = 0; u < 2; ++u) {
      int ti = tt + u;
      u16x4 kv4 = u ? kvB : kvA;
      u16x2 sv = u ? svB : svA;
      float k0 = bf2f(kv4[0]), v0 = bf2f(kv4[1]);
      float k1 = bf2f(kv4[2]), v1 = bf2f(kv4[3]);
      float e0 = __expf(k0), e1 = __expf(k1);
      if (ti >= t0) {
        float t0e = e0 * eu0, t1e = e1 * eu1;
        float y0 = fmaf(t0e, v0, P0) * __builtin_amdgcn_rcpf(Q0 + t0e);
        float y1 = fmaf(t1e, v1, P1) * __builtin_amdgcn_rcpf(Q1 + t1e);
        u16x2 ow;
        ow[0] = f2bf(y0 * bf2f(sv[0]));
        ow[1] = f2bf(y1 * bf2f(sv[1]));
        *(u16x2*)(xssr + (bT + ti) * 1024 + scol + c0) = ow;
      }
      P0 = fmaf(P0, D0, e0 * v0);
      Q0 = fmaf(Q0, D0, e0);
      P1 = fmaf(P1, D1, e1 * v1);
      Q1 = fmaf(Q1, D1, e1);
    }
    kvA = kvC; kvB = kvD;
    svA = svC; svB = svD;
  }
}

// ---------------- launch ----------------
extern "C" void kernel_launch(void* const* d_in, const int* in_sizes, int n_in,
                              void* d_out, int out_size, void* d_ws, size_t ws_size,
                              hipStream_t stream) {
  const float* x      = (const float*)d_in[0];
  const float* alpha  = (const float*)d_in[1];
  const float* dw1    = (const float*)d_in[2];
  const float* dw3    = (const float*)d_in[3];
  const float* dw5    = (const float*)d_in[4];
  const float* Wk     = (const float*)d_in[5];
  const float* Wv     = (const float*)d_in[6];
  const float* Wr     = (const float*)d_in[7];
  const float* Wf     = (const float*)d_in[8];
  const float* bfv    = (const float*)d_in[9];
  const float* Wb     = (const float*)d_in[10];
  const float* bbv    = (const float*)d_in[11];
  const float* sdecay = (const float*)d_in[12];
  const float* sfirst = (const float*)d_in[13];
  const float* Wo     = (const float*)d_in[14];
  (void)n_in; (void)out_size; (void)ws_size;

  const int Bn = in_sizes[0] / (4096 * 256);  // 8
  const int MT = Bn * 4096;                    // 32768

  char* ws = (char*)d_ws;
  size_t off = 0;
  auto alloc = [&](size_t bytes) {
    void* p = ws + off;
    off += (bytes + 255) & ~(size_t)255;
    return p;
  };
  short* xf            = (short*)alloc((size_t)MT * 256 * 2);
  unsigned short* kv   = (unsigned short*)alloc((size_t)MT * 1024 * 2);
  unsigned short* srb  = (unsigned short*)alloc((size_t)MT * 256 * 2);
  unsigned short* xssr = (unsigned short*)alloc((size_t)MT * 1024 * 2);
  short* wcat          = (short*)alloc((size_t)1280 * 256 * 2);
  float* bias          = (float*)alloc(1280 * 4);
  float* weff          = (float*)alloc(25 * 256 * 4);
  short* wob           = (short*)alloc((size_t)256 * 1024 * 2);

  k_weff<<<25, 256, 0, stream>>>(alpha, dw1, dw3, dw5, weff);
  k_combine<<<1280, 256, 0, stream>>>(Wk, Wv, Wr, Wf, Wb, bfv, bbv, wcat, bias);
  k_wo<<<1024, 256, 0, stream>>>(Wo, wob);
  k_shift<<<dim3(8, 32, Bn), 256, 0, stream>>>(x, weff, (unsigned short*)xf);
  // gemm1: flat 2560-block grid, XCD A-locality (NT=10), 4 blocks/CU (R6 exact).
  gemm_bt<0, 128, 64, 10><<<dim3(MT / 128 * 10), 256, 0, stream>>>(
      xf, wcat, bias, kv, srb, MT, 1280, 256);
  // wkv: chunk 64 (warmup amortized 1.5x -> 1.25x), 1024 blocks.
  k_wkv<<<dim3(64, 2, Bn), 256, 0, stream>>>(kv, srb, sdecay, sfirst, xssr);
  // gemm2: deep pipe (NK=16), natural grid, 3 blocks/CU (R4 exact).
  gemm_db<1, 64, 64><<<dim3(MT / 64, 2), 256, 0, stream>>>(
      (const short*)xssr, wob, nullptr, d_out, nullptr, MT, 256, 1024);
}

// Round 11
// 150.188 us; speedup vs baseline: 2.2043x; 1.0441x over previous
//
#include <hip/hip_runtime.h>

typedef __attribute__((ext_vector_type(8))) short bf16x8;
typedef __attribute__((ext_vector_type(4))) float f32x4;
typedef __attribute__((ext_vector_type(4))) unsigned short u16x4;
typedef __attribute__((ext_vector_type(2))) unsigned short u16x2;
typedef __attribute__((ext_vector_type(8))) unsigned short u16x8;

#define GLD16(g, l) __builtin_amdgcn_global_load_lds( \
    (const __attribute__((address_space(1))) void*)(g), \
    (__attribute__((address_space(3))) void*)(l), 16, 0, 0)

__device__ __forceinline__ unsigned short f2bf(float f) {
  unsigned u = __float_as_uint(f);
  unsigned r = u + 0x7FFFu + ((u >> 16) & 1u);
  return (unsigned short)(r >> 16);
}
__device__ __forceinline__ float bf2f(unsigned short h) {
  return __uint_as_float(((unsigned)h) << 16);
}

template <int N>
__device__ __forceinline__ void wait_vm() {
  if constexpr (N == 0) asm volatile("s_waitcnt vmcnt(0)" ::: "memory");
  else if constexpr (N == 6) asm volatile("s_waitcnt vmcnt(6)" ::: "memory");
  else static_assert(N == 0, "unsupported vmcnt");
}

// ---------------- prep kernels ----------------

__global__ void k_weff(const float* __restrict__ alpha,
                       const float* __restrict__ dw1,
                       const float* __restrict__ dw3,
                       const float* __restrict__ dw5,
                       float* __restrict__ weff) {
  int tap = blockIdx.x;        // 0..24
  int c = threadIdx.x;         // 0..255
  int dy = tap / 5, dx = tap % 5;
  float v = alpha[3] * dw5[c * 25 + tap];
  if (dy >= 1 && dy <= 3 && dx >= 1 && dx <= 3)
    v += alpha[2] * dw3[c * 9 + (dy - 1) * 3 + (dx - 1)];
  if (tap == 12) v += alpha[1] * dw1[c] + alpha[0];
  weff[tap * 256 + c] = v;
}

// combined weights with INTERLEAVED kv row order (R14-verified harmless, kept).
// Row map: k1[c]->2c, v1[c]->2c+1, k3[c]->512+2c, v3[c]->512+2c+1, Wr[c]->1024+c.
__global__ void k_combine(const float* __restrict__ Wk,
                          const float* __restrict__ Wv,
                          const float* __restrict__ Wr,
                          const float* __restrict__ Wf,
                          const float* __restrict__ Wb,
                          const float* __restrict__ bfv,
                          const float* __restrict__ bbv,
                          short* __restrict__ wcat,
                          float* __restrict__ bias) {
  int mat = blockIdx.x >> 8;   // 0:k1 1:k3 2:v1 3:v3 4:r
  int i = blockIdx.x & 255;
  int j = threadIdx.x;
  if (mat == 4) {
    wcat[(size_t)(1024 + i) * 256 + j] = (short)f2bf(Wr[i * 256 + j]);
    if (j == 0) bias[1024 + i] = 0.f;
    return;
  }
  const float* Am = (mat & 1) ? Wb : Wf;
  const float* Bm = (mat < 2) ? Wk : Wv;
  const float* arow = Am + i * 256;
  float acc = 0.f;
  for (int m = 0; m < 256; ++m) acc += arow[m] * Bm[m * 256 + j];
  int newrow = ((mat & 1) << 9) + (i << 1) + (mat >> 1);  // interleaved position
  wcat[(size_t)newrow * 256 + j] = (short)f2bf(acc);
  if (j == 0) bias[newrow] = (mat & 1) ? bbv[i] : bfv[i];
}

__global__ void k_wo(const float* __restrict__ Wo, short* __restrict__ wob) {
  int i = blockIdx.x * 256 + threadIdx.x;
  wob[i] = (short)f2bf(Wo[i]);
}

// ---------------- OmniShift: 2-row register sliding-window 5x5 stencil ----------
// R13-verified: w-tile 8, 2048 blocks = 8 blocks/CU.
// R26: (a) XCD h-stripe swizzle (T1 mechanism, in-session-verified on gemm1):
// consecutive default bids = same rows but round-robin to 8 XCDs, so the 3x row
// re-reads were served by L3. Now xcd=bid&7 owns h-blocks [xcd*4, xcd*4+4);
// within an XCD: w fastest (8 blocks, identical rows), then hb (4/6 rows
// shared), then b. Working set 6 rows x 64 w x 256 c x 4B = 384 KB << 4MB L2.
// (b) launch_bounds (256,8)->(256,6): 8 waves/EU capped VGPR at 64 but the
// kernel wants ~90 (win 48 + wg 25 + addressing) -> spill risk. Cap 85 now,
// 6 blocks/CU = 24 waves/CU (ample for this load-rich streaming kernel).
__global__ __launch_bounds__(256, 6)
void k_shift(const float* __restrict__ x, const float* __restrict__ weff,
             unsigned short* __restrict__ xf) {
  int c = threadIdx.x;
  int xcd = blockIdx.x & 7;
  int j = blockIdx.x >> 3;
  int wb = j & 7;              // w-block (fastest: shares identical rows)
  int hb = (j >> 3) & 3;       // h-block within this XCD's stripe
  int b = j >> 5;              // batch (slowest)
  int w0 = wb * 8;             // 0,8,...,56
  int h0 = (xcd * 4 + hb) * 2; // 0..62

  float wg[5][5];
#pragma unroll
  for (int dy = 0; dy < 5; ++dy)
#pragma unroll
    for (int dx = 0; dx < 5; ++dx)
      wg[dy][dx] = weff[(dy * 5 + dx) * 256 + c];

  const float* xb = x + (size_t)b * 4096 * 256 + c;
  int rowoff[6];
  bool rv[6];
#pragma unroll
  for (int r = 0; r < 6; ++r) {
    int y = h0 + r - 2;
    rv[r] = (y >= 0 && y < 64);
    int yc = y < 0 ? 0 : (y > 63 ? 63 : y);
    rowoff[r] = yc * 64 * 256;
  }

  float win[6][8];
#pragma unroll
  for (int j2 = -2; j2 <= 1; ++j2) {
    int xx = w0 + j2;
    int slot = j2 & 7;                // w0 % 8 == 0 -> static
    bool xv = (xx >= 0);
    int xc = xx < 0 ? 0 : xx;
#pragma unroll
    for (int r = 0; r < 6; ++r) {
      float v = xb[rowoff[r] + xc * 256];
      win[r][slot] = (xv && rv[r]) ? v : 0.f;
    }
  }

  unsigned short* xo = xf + ((size_t)b * 4096 + (size_t)h0 * 64) * 256 + c;
#pragma unroll
  for (int ui = 0; ui < 8; ++ui) {
    int w = w0 + ui;
    {
      int xx = w + 2;
      int slot = (ui + 2) & 7;        // static
      bool xv = (xx < 64);
      int xc = xx > 63 ? 63 : xx;
#pragma unroll
      for (int r = 0; r < 6; ++r) {
        float v = xb[rowoff[r] + xc * 256];
        win[r][slot] = (xv && rv[r]) ? v : 0.f;
      }
    }
#pragma unroll
    for (int j2 = 0; j2 < 2; ++j2) {
      float a0 = 0.f, a1 = 0.f, a2 = 0.f, a3 = 0.f, a4 = 0.f;
#pragma unroll
      for (int dx = 0; dx < 5; ++dx) {
        int slot = (ui - 2 + dx) & 7; // static
        a0 = fmaf(win[j2 + 0][slot], wg[0][dx], a0);
        a1 = fmaf(win[j2 + 1][slot], wg[1][dx], a1);
        a2 = fmaf(win[j2 + 2][slot], wg[2][dx], a2);
        a3 = fmaf(win[j2 + 3][slot], wg[3][dx], a3);
        a4 = fmaf(win[j2 + 4][slot], wg[4][dx], a4);
      }
      xo[((size_t)j2 * 64 + w) * 256] = f2bf(((a0 + a1) + (a2 + a3)) + a4);
    }
  }
}

// ---------------- gemm1: single-buffer bf16 MFMA GEMM (R6 exact, BEST) ----------
// out[M][N] = A[M][K] * B[N][K]^T. 128x128 tile, BK=64, 4 waves (2x2), 16x16x32.
// (256,4): VGPR 60, no spill. REGISTER WALL (R5/R8/R9): acc must stay <= 64 f32
// per thread -- (256,5), 512-thread, and 2-n-tile variants all spill 2-10x.
// This structure's ~52 us is its ceiling; do not grow work/block here.
// XOR swizzle on stage-source chunk + ds_read addr (0 conflicts, verified).
// NT>0: XCD A-locality flat grid (R19-verified: FETCH 27->14.5 MB, 60->52 us):
// xcd=bid&7 owns M/BM/8 contiguous m-tiles, NT n-tiles temporally adjacent.
template <int EPI, int BM, int BK, int NT>
__global__ __launch_bounds__(256, (BK == 128) ? 3 : 4)
void gemm_bt(const short* __restrict__ A, const short* __restrict__ Bm,
             const float* __restrict__ bias,
             void* __restrict__ O0, void* __restrict__ O1,
             int M, int N, int K) {
  constexpr int AE = BM * BK;          // shorts in A buffer
  constexpr int MI = BM / 32;          // m-fragments per wave
  constexpr int CH = BK / 8;           // 16B chunks per row
  constexpr int LA = BM * BK / 2048;   // A gld_lds per thread
  constexpr int LB = BK / 16;          // B gld_lds per thread
  constexpr int RW = 132;              // padded row width for epilogue (f32)
  __shared__ __align__(16) short lds[AE + 128 * BK];

  int t = threadIdx.x;
  int lane = t & 63, wv = t >> 6;
  int wr = wv >> 1, wc = wv & 1;
  int m0, n0;
  if (NT) {
    int x = blockIdx.x & 7;
    int j = blockIdx.x >> 3;
    int mpx = M / (BM * 8);            // m-tiles per XCD
    m0 = (x * mpx + j / NT) * BM;
    n0 = (j % NT) * 128;
  } else {
    m0 = blockIdx.x * BM;
    n0 = blockIdx.y * 128;
  }
  f32x4 acc[MI][4] = {};

  for (int k0 = 0; k0 < K; k0 += BK) {
    // STAGE: linear LDS dest, swizzled global source chunk
#pragma unroll
    for (int i = 0; i < LA; ++i) {
      int cc = t + i * 256;
      int row = cc / CH, kc = cc % CH;
      GLD16(A + (size_t)(m0 + row) * K + k0 + ((kc ^ (row & (CH - 1))) << 3), &lds[cc * 8]);
    }
#pragma unroll
    for (int i = 0; i < LB; ++i) {
      int cc = t + i * 256;
      int row = cc / CH, kc = cc % CH;
      GLD16(Bm + (size_t)(n0 + row) * K + k0 + ((kc ^ (row & (CH - 1))) << 3), &lds[AE + cc * 8]);
    }
    __syncthreads();
    // COMPUTE: same XOR on ds_read address
#pragma unroll
    for (int kk = 0; kk < BK / 32; ++kk) {
      int ch = kk * 4 + (lane >> 4);
      bf16x8 av[MI], bv[4];
#pragma unroll
      for (int i = 0; i < MI; ++i) {
        int row = wr * (BM / 2) + i * 16 + (lane & 15);
        av[i] = *(const bf16x8*)&lds[row * BK + ((ch ^ (row & (CH - 1))) << 3)];
      }
#pragma unroll
      for (int i = 0; i < 4; ++i) {
        int row = wc * 64 + i * 16 + (lane & 15);
        bv[i] = *(const bf16x8*)&lds[AE + row * BK + ((ch ^ (row & (CH - 1))) << 3)];
      }
#pragma unroll
      for (int mi = 0; mi < MI; ++mi)
#pragma unroll
        for (int ni = 0; ni < 4; ++ni)
          acc[mi][ni] = __builtin_amdgcn_mfma_f32_16x16x32_bf16(av[mi], bv[ni], acc[mi][ni], 0, 0, 0);
    }
    __syncthreads();
  }

  // ---- epilogue: LDS transpose (row-major fl) -> coalesced wide stores ----
  float* fl = (float*)lds;   // [32 rows][RW cols] f32 = 16.9 KB
  float bb[4];
  if (EPI == 0) {
#pragma unroll
    for (int ni = 0; ni < 4; ++ni)
      bb[ni] = bias[n0 + wc * 64 + ni * 16 + (lane & 15)];
  }
  int rrow = t >> 3;               // 0..31
  int colb = (t & 7) * 16;
#pragma unroll
  for (int mi = 0; mi < MI; ++mi) {
    if (mi) __syncthreads();       // previous readout done before overwrite
    {
      int r0 = (lane >> 4) * 4;
#pragma unroll
      for (int ni = 0; ni < 4; ++ni) {
        int colL = wc * 64 + (lane & 15) + ni * 16;
        f32x4 v = acc[mi][ni];
#pragma unroll
        for (int j = 0; j < 4; ++j) {
          float vj = v[j];
          if (EPI == 0) vj += bb[ni];
          fl[(wr * 16 + r0 + j) * RW + colL] = vj;
        }
      }
    }
    __syncthreads();
    float vv[16];
#pragma unroll
    for (int q = 0; q < 4; ++q)
      *(f32x4*)&vv[q * 4] = *(const f32x4*)&fl[rrow * RW + colb + q * 4];
    int grow = m0 + (rrow >> 4) * (BM / 2) + mi * 16 + (rrow & 15);
    if (EPI == 0) {
      u16x8 o0, o1;
      if (n0 < 1024) {
#pragma unroll
        for (int q = 0; q < 8; ++q) { o0[q] = f2bf(vv[q]); o1[q] = f2bf(vv[8 + q]); }
        unsigned short* dst = (unsigned short*)O0 + (size_t)grow * 1024 + n0 + colb;
        *(u16x8*)dst = o0;
        *(u16x8*)(dst + 8) = o1;
      } else {
#pragma unroll
        for (int q = 0; q < 8; ++q) {
          o0[q] = f2bf(1.f / (1.f + __expf(-vv[q])));
          o1[q] = f2bf(1.f / (1.f + __expf(-vv[8 + q])));
        }
        unsigned short* dst = (unsigned short*)O1 + (size_t)grow * 256 + (n0 - 1024) + colb;
        *(u16x8*)dst = o0;
        *(u16x8*)(dst + 8) = o1;
      }
    } else {
      float* dst = (float*)O0 + (size_t)grow * N + n0 + colb;
#pragma unroll
      for (int q = 0; q < 4; ++q) {
        f32x4 ov = {vv[q * 4], vv[q * 4 + 1], vv[q * 4 + 2], vv[q * 4 + 3]};
        *(f32x4*)(dst + q * 4) = ov;
      }
    }
  }
}

// ---------------- gemm2: double-buffered deep pipeline (R4 exact) ---------------
// R4-verified ~19 us (~900 TF): BM=64/BK=64, NK=16, depth-2 counted-vmcnt
// pipeline, 3 blocks/CU, natural dim3(M/64, 2) grid (R5: XCD remap hurt here).
// Per iter: wait vmcnt(LD) (current step's loads; next step's stay in flight
// ACROSS the barrier), s_barrier, compute, lgkmcnt(0)+s_barrier, stage k+2.
// NEVER __syncthreads in the K-loop (drains vmcnt(0), kills the pipe).
template <int EPI, int BM, int BK>
__global__ __launch_bounds__(256, 3)
void gemm_db(const short* __restrict__ A, const short* __restrict__ Bm,
             const float* __restrict__ bias,
             void* __restrict__ O0, void* __restrict__ O1,
             int M, int N, int K) {
  constexpr int AE = BM * BK;           // shorts in A region of one buffer
  constexpr int BUFS = (BM + 128) * BK; // shorts per buffer
  constexpr int MI = BM / 32;           // m-fragments per wave
  constexpr int CH = BK / 8;            // 16B chunks per row
  constexpr int LA = BM * BK / 2048;    // A gld_lds per thread per step
  constexpr int LB = BK / 16;           // B gld_lds per thread per step
  constexpr int LD = LA + LB;           // loads in flight per step
  constexpr int RW = 132;               // padded row width for epilogue (f32)
  __shared__ __align__(16) short lds[2 * BUFS];

  int t = threadIdx.x;
  int lane = t & 63, wv = t >> 6;
  int wr = wv >> 1, wc = wv & 1;
  int m0 = blockIdx.x * BM, n0 = blockIdx.y * 128;
  const int NK = K / BK;
  f32x4 acc[MI][4] = {};

  float bb[4];
  if (EPI == 0) {
#pragma unroll
    for (int ni = 0; ni < 4; ++ni)
      bb[ni] = bias[n0 + wc * 64 + ni * 16 + (lane & 15)];
  }

  auto STAGE = [&](int step, int bo) {
    int k0 = step * BK;
#pragma unroll
    for (int i = 0; i < LA; ++i) {
      int cc = t + i * 256;
      int row = cc / CH, kc = cc % CH;
      GLD16(A + (size_t)(m0 + row) * K + k0 + ((kc ^ (row & (CH - 1))) << 3),
            &lds[bo + cc * 8]);
    }
#pragma unroll
    for (int i = 0; i < LB; ++i) {
      int cc = t + i * 256;
      int row = cc / CH, kc = cc % CH;
      GLD16(Bm + (size_t)(n0 + row) * K + k0 + ((kc ^ (row & (CH - 1))) << 3),
            &lds[bo + AE + cc * 8]);
    }
  };
  auto COMPUTE = [&](int bo) {
#pragma unroll
    for (int kk = 0; kk < BK / 32; ++kk) {
      int ch = kk * 4 + (lane >> 4);
      bf16x8 av[MI], bv[4];
#pragma unroll
      for (int i = 0; i < MI; ++i) {
        int row = wr * (BM / 2) + i * 16 + (lane & 15);
        av[i] = *(const bf16x8*)&lds[bo + row * BK + ((ch ^ (row & (CH - 1))) << 3)];
      }
#pragma unroll
      for (int i = 0; i < 4; ++i) {
        int row = wc * 64 + i * 16 + (lane & 15);
        bv[i] = *(const bf16x8*)&lds[bo + AE + row * BK + ((ch ^ (row & (CH - 1))) << 3)];
      }
#pragma unroll
      for (int mi = 0; mi < MI; ++mi)
#pragma unroll
        for (int ni = 0; ni < 4; ++ni)
          acc[mi][ni] = __builtin_amdgcn_mfma_f32_16x16x32_bf16(av[mi], bv[ni], acc[mi][ni], 0, 0, 0);
    }
  };

  STAGE(0, 0);
  STAGE(1, BUFS);
#pragma unroll
  for (int k = 0; k < 16; ++k) {      // bounded by max NK; break inside
    if (k >= NK) break;
    int bo = (k & 1) ? BUFS : 0;
    if (k < NK - 1) wait_vm<LD>();
    else wait_vm<0>();
    __builtin_amdgcn_s_barrier();
    COMPUTE(bo);
    asm volatile("s_waitcnt lgkmcnt(0)" ::: "memory");
    __builtin_amdgcn_s_barrier();
    if (k + 2 < NK) STAGE(k + 2, bo);
  }

  // ---- epilogue: LDS transpose (row-major fl) -> coalesced wide stores ----
  float* fl = (float*)lds;   // [32 rows][RW cols] f32 = 16.9 KB
  int rrow = t >> 3;               // 0..31
  int colb = (t & 7) * 16;
#pragma unroll
  for (int mi = 0; mi < MI; ++mi) {
    if (mi) __syncthreads();       // previous readout done before overwrite
    {
      int r0 = (lane >> 4) * 4;
#pragma unroll
      for (int ni = 0; ni < 4; ++ni) {
        int colL = wc * 64 + (lane & 15) + ni * 16;
        f32x4 v = acc[mi][ni];
#pragma unroll
        for (int j = 0; j < 4; ++j) {
          float vj = v[j];
          if (EPI == 0) vj += bb[ni];
          fl[(wr * 16 + r0 + j) * RW + colL] = vj;
        }
      }
    }
    __syncthreads();
    float vv[16];
#pragma unroll
    for (int q = 0; q < 4; ++q)
      *(f32x4*)&vv[q * 4] = *(const f32x4*)&fl[rrow * RW + colb + q * 4];
    int grow = m0 + (rrow >> 4) * (BM / 2) + mi * 16 + (rrow & 15);
    if (EPI == 0) {
      u16x8 o0, o1;
      if (n0 < 1024) {
#pragma unroll
        for (int q = 0; q < 8; ++q) { o0[q] = f2bf(vv[q]); o1[q] = f2bf(vv[8 + q]); }
        unsigned short* dst = (unsigned short*)O0 + (size_t)grow * 1024 + n0 + colb;
        *(u16x8*)dst = o0;
        *(u16x8*)(dst + 8) = o1;
      } else {
#pragma unroll
        for (int q = 0; q < 8; ++q) {
          o0[q] = f2bf(1.f / (1.f + __expf(-vv[q])));
          o1[q] = f2bf(1.f / (1.f + __expf(-vv[8 + q])));
        }
        unsigned short* dst = (unsigned short*)O1 + (size_t)grow * 256 + (n0 - 1024) + colb;
        *(u16x8*)dst = o0;
        *(u16x8*)(dst + 8) = o1;
      }
    } else {
      float* dst = (float*)O0 + (size_t)grow * N + n0 + colb;
#pragma unroll
      for (int q = 0; q < 4; ++q) {
        f32x4 ov = {vv[q * 4], vv[q * 4 + 1], vv[q * 4 + 2], vv[q * 4 + 3]};
        *(f32x4*)(dst + q * 4) = ov;
      }
    }
  }
}

// ---------------- WKV (software-pipelined; 2 ch/thread, interleaved kv) ---------
// R15-verified prefetch pipeline (4-6 outstanding loads/wave).
// R25-verified: chunk 64 (warmup amp 1.5x -> 1.25x) bought ~6.5 us.
// chunk 128 NOT taken: saves only ~9% more reads but halves blocks to 2/CU.
// grid 64 x 2(tr) x 8 = 1024 blocks = 4/CU = 16 waves/CU.
__global__ __launch_bounds__(256, 8)
void k_wkv(const unsigned short* __restrict__ kvb, const unsigned short* __restrict__ srb,
           const float* __restrict__ decay, const float* __restrict__ first,
           unsigned short* __restrict__ xssr) {
  const int T = 4096;
  int tid = threadIdx.x;
  int g = tid >> 7;              // 0: k1/v1 half, 1: k3/v3 half
  int l = tid & 127;
  int c0 = l * 2;
  int tr = blockIdx.y;           // 0 natural, 1 transposed scan order
  int s = (g << 1) | tr;         // stream in concat order k1,k2,k3,k4
  int scol = s * 256;
  int chunk = blockIdx.x;        // 0..63, 64 tokens each
  int b = blockIdx.z;
  const float invT = 1.0f / 4096.0f;

  float P0 = 0.f, P1 = 0.f, Q0 = 0.f, Q1 = 0.f;
  float D0 = __expf(-__expf(decay[scol + c0] * invT));
  float D1 = __expf(-__expf(decay[scol + c0 + 1] * invT));
  float eu0 = __expf(first[scol + c0] * invT);
  float eu1 = __expf(first[scol + c0 + 1] * invT);

  int t0 = chunk * 64;
  int tstart = t0 >= 16 ? t0 - 16 : 0;  // 16-step warmup: weight < e^-16 ~ 1e-7
  int tend = t0 + 64;                   // (tend - tstart) is 64 or 80: even
  const size_t bT = (size_t)b * T;
  const int kvoff = (g << 9) + (c0 << 1);  // [half][c][k|v] in shorts

  auto kvload = [&](int tt) {
    int tok = tr ? (((tt & 63) << 6) | (tt >> 6)) : tt;
    return *(const u16x4*)(kvb + (bT + tok) * 1024 + kvoff);
  };
  auto srload = [&](int tt) {
    return *(const u16x2*)(srb + (bT + tt) * 256 + c0);
  };

  // pipeline prologue: 2 iterations in flight
  u16x4 kvA = kvload(tstart);
  u16x4 kvB = kvload(tstart + 1);
  u16x2 svA = srload(tstart);
  u16x2 svB = srload(tstart + 1);

  for (int tt = tstart; tt < tend; tt += 2) {
    // prefetch tt+2 / tt+3 (clamped: last iter re-reads tend-1, harmless)
    int tp2 = tt + 2 < tend ? tt + 2 : tend - 1;
    int tp3 = tt + 3 < tend ? tt + 3 : tend - 1;
    u16x4 kvC = kvload(tp2);
    u16x4 kvD = kvload(tp3);
    u16x2 svC = srload(tp2);
    u16x2 svD = srload(tp3);

#pragma unroll
    for (int u = 0; u < 2; ++u) {
      int ti = tt + u;
      u16x4 kv4 = u ? kvB : kvA;
      u16x2 sv = u ? svB : svA;
      float k0 = bf2f(kv4[0]), v0 = bf2f(kv4[1]);
      float k1 = bf2f(kv4[2]), v1 = bf2f(kv4[3]);
      float e0 = __expf(k0), e1 = __expf(k1);
      if (ti >= t0) {
        float t0e = e0 * eu0, t1e = e1 * eu1;
        float y0 = fmaf(t0e, v0, P0) * __builtin_amdgcn_rcpf(Q0 + t0e);
        float y1 = fmaf(t1e, v1, P1) * __builtin_amdgcn_rcpf(Q1 + t1e);
        u16x2 ow;
        ow[0] = f2bf(y0 * bf2f(sv[0]));
        ow[1] = f2bf(y1 * bf2f(sv[1]));
        *(u16x2*)(xssr + (bT + ti) * 1024 + scol + c0) = ow;
      }
      P0 = fmaf(P0, D0, e0 * v0);
      Q0 = fmaf(Q0, D0, e0);
      P1 = fmaf(P1, D1, e1 * v1);
      Q1 = fmaf(Q1, D1, e1);
    }
    kvA = kvC; kvB = kvD;
    svA = svC; svB = svD;
  }
}

// ---------------- launch ----------------
extern "C" void kernel_launch(void* const* d_in, const int* in_sizes, int n_in,
                              void* d_out, int out_size, void* d_ws, size_t ws_size,
                              hipStream_t stream) {
  const float* x      = (const float*)d_in[0];
  const float* alpha  = (const float*)d_in[1];
  const float* dw1    = (const float*)d_in[2];
  const float* dw3    = (const float*)d_in[3];
  const float* dw5    = (const float*)d_in[4];
  const float* Wk     = (const float*)d_in[5];
  const float* Wv     = (const float*)d_in[6];
  const float* Wr     = (const float*)d_in[7];
  const float* Wf     = (const float*)d_in[8];
  const float* bfv    = (const float*)d_in[9];
  const float* Wb     = (const float*)d_in[10];
  const float* bbv    = (const float*)d_in[11];
  const float* sdecay = (const float*)d_in[12];
  const float* sfirst = (const float*)d_in[13];
  const float* Wo     = (const float*)d_in[14];
  (void)n_in; (void)out_size; (void)ws_size;

  const int Bn = in_sizes[0] / (4096 * 256);  // 8
  const int MT = Bn * 4096;                    // 32768

  char* ws = (char*)d_ws;
  size_t off = 0;
  auto alloc = [&](size_t bytes) {
    void* p = ws + off;
    off += (bytes + 255) & ~(size_t)255;
    return p;
  };
  short* xf            = (short*)alloc((size_t)MT * 256 * 2);
  unsigned short* kv   = (unsigned short*)alloc((size_t)MT * 1024 * 2);
  unsigned short* srb  = (unsigned short*)alloc((size_t)MT * 256 * 2);
  unsigned short* xssr = (unsigned short*)alloc((size_t)MT * 1024 * 2);
  short* wcat          = (short*)alloc((size_t)1280 * 256 * 2);
  float* bias          = (float*)alloc(1280 * 4);
  float* weff          = (float*)alloc(25 * 256 * 4);
  short* wob           = (short*)alloc((size_t)256 * 1024 * 2);

  k_weff<<<25, 256, 0, stream>>>(alpha, dw1, dw3, dw5, weff);
  k_combine<<<1280, 256, 0, stream>>>(Wk, Wv, Wr, Wf, Wb, bfv, bbv, wcat, bias);
  k_wo<<<1024, 256, 0, stream>>>(Wo, wob);
  // shift: flat 2048-block grid, XCD h-stripe swizzle (see kernel comment).
  k_shift<<<256 * Bn * 8 / 8 * 8 / 8, 256, 0, stream>>>(x, weff, (unsigned short*)xf);
  // gemm1: flat 2560-block grid, XCD A-locality (NT=10), 4 blocks/CU (R6 exact).
  gemm_bt<0, 128, 64, 10><<<dim3(MT / 128 * 10), 256, 0, stream>>>(
      xf, wcat, bias, kv, srb, MT, 1280, 256);
  // wkv: chunk 64 (R25-verified), 1024 blocks.
  k_wkv<<<dim3(64, 2, Bn), 256, 0, stream>>>(kv, srb, sdecay, sfirst, xssr);
  // gemm2: deep pipe (NK=16), natural grid, 3 blocks/CU (R4 exact).
  gemm_db<1, 64, 64><<<dim3(MT / 64, 2), 256, 0, stream>>>(
      (const short*)xssr, wob, nullptr, d_out, nullptr, MT, 256, 1024);
}